// Round 1
// baseline (895.538 us; speedup 1.0000x reference)
//
#include <hip/hip_runtime.h>

#define NS 32
#define WID 128
#define NHID 3
#define NPTS 262144
#define PTILE 128
#define TMLP 512
#define TPB 160  // tiles per bin: capacity 20480 tasks/bin (expected ~16.4K +- 124)

#define TASKS_OFF 512
#define WT_OFF (TASKS_OFF + 2 * NPTS * 4)

__device__ __forceinline__ float tanh_fast(float v) {
    // tanh(v) = 1 - 2/(exp2(v*2*log2e)+1); monotone, saturates correctly, ~1e-6 abs err
    float a = v * 2.8853900817779268f;
    float e; asm("v_exp_f32 %0, %1" : "=v"(e) : "v"(a));
    float d = e + 1.0f;
    float r; asm("v_rcp_f32 %0, %1" : "=v"(r) : "v"(d));
    return fmaf(-2.0f, r, 1.0f);
}

__device__ __forceinline__ float coswin(float u) {
    // cos(pi/2 * u)^2 for |u|<1 else 0; v_cos takes revolutions: cos(2*pi*(u/4))
    if (fabsf(u) >= 1.0f) return 0.0f;
    float rev = u * 0.25f;
    float c; asm("v_cos_f32 %0, %1" : "=v"(c) : "v"(rev));
    return c * c;
}

// ---------------- bucketing ----------------

__global__ void k_count(const float* __restrict__ x, int* __restrict__ counts, int n) {
    __shared__ int loc[NS];
    int t = threadIdx.x;
    if (t < NS) loc[t] = 0;
    __syncthreads();
    int i = blockIdx.x * blockDim.x + t;
    if (i < n) {
        float tt = x[i] * 32.0f;
        int j = (int)floorf(tt); j = min(max(j, 0), 31);
        atomicAdd(&loc[j], 1);
        float u = tt - (float)j - 0.5f;
        int nb = (u > 0.0f) ? j + 1 : j - 1;
        if (u != 0.0f && nb >= 0 && nb < NS) atomicAdd(&loc[nb], 1);
    }
    __syncthreads();
    if (t < NS) atomicAdd(&counts[t], loc[t]);
}

__global__ void k_scan(const int* __restrict__ counts, int* __restrict__ offsets,
                       int* __restrict__ cursors) {
    if (threadIdx.x == 0) {
        int acc = 0;
        for (int s = 0; s < NS; ++s) { offsets[s] = acc; cursors[s] = acc; acc += counts[s]; }
    }
}

__global__ void k_scatter(const float* __restrict__ x, int* __restrict__ cursors,
                          int* __restrict__ tasks, int n) {
    __shared__ int loc[NS];
    __shared__ int base[NS];
    int t = threadIdx.x;
    if (t < NS) loc[t] = 0;
    __syncthreads();
    int i = blockIdx.x * blockDim.x + t;
    int j = -1, nb = -1, sj = 0, snb = 0;
    if (i < n) {
        float tt = x[i] * 32.0f;
        j = min(max((int)floorf(tt), 0), 31);
        sj = atomicAdd(&loc[j], 1);
        float u = tt - (float)j - 0.5f;
        int nb2 = (u > 0.0f) ? j + 1 : j - 1;
        if (u != 0.0f && nb2 >= 0 && nb2 < NS) { nb = nb2; snb = atomicAdd(&loc[nb], 1); }
    }
    __syncthreads();
    if (t < NS) base[t] = atomicAdd(&cursors[t], loc[t]);
    __syncthreads();
    if (i < n) {
        tasks[base[j] + sj] = i;
        if (nb >= 0) tasks[base[nb] + snb] = i;
    }
}

// ---------------- W_hid transpose: Wt[s][l][k][o] = W[s][l][o][k] ----------------

__global__ void k_transpose(const float* __restrict__ Wh, float* __restrict__ Wt) {
    __shared__ float tile[32][33];
    int m  = blockIdx.x >> 4;        // matrix 0..95
    int tr = (blockIdx.x >> 2) & 3;  // o-tile
    int tc = blockIdx.x & 3;         // k-tile
    const float* src = Wh + (size_t)m * 16384;
    float* dst = Wt + (size_t)m * 16384;
    int lx = threadIdx.x, ly = threadIdx.y;  // 32 x 8
    for (int yy = ly; yy < 32; yy += 8)
        tile[yy][lx] = src[(tr * 32 + yy) * WID + tc * 32 + lx];
    __syncthreads();
    for (int yy = ly; yy < 32; yy += 8)
        dst[(tc * 32 + yy) * WID + tr * 32 + lx] = tile[lx][yy];
}

// ---------------- main fused MLP ----------------

__global__ __launch_bounds__(TMLP, 2) void k_mlp(
    const float* __restrict__ x, const float* __restrict__ W_in, const float* __restrict__ b_in,
    const float* __restrict__ b_hid, const float* __restrict__ W_out, const float* __restrict__ b_out,
    const float* __restrict__ centers, const float* __restrict__ scales,
    const int* __restrict__ counts, const int* __restrict__ offsets, const int* __restrict__ tasks,
    const float* __restrict__ WtG, float* __restrict__ out) {

    const int bin = blockIdx.y;
    const int tile = blockIdx.x;
    const int cnt = counts[bin];
    if (tile * PTILE >= cnt) return;
    const int start = offsets[bin];

    __shared__ __align__(16) float lWt[WID * WID];  // Wt[k][o], 64KB
    __shared__ __align__(16) float lH[WID * WID];   // ht[neuron][p], XOR-swizzled cols, 64KB
    __shared__ float lU[PTILE], lWgt[PTILE];
    __shared__ int lTid[PTILE];
    __shared__ float lWin[WID], lBinp[WID], lWo[WID], lBb[WID];
    __shared__ float lRed[4 * PTILE];

    const int t = threadIdx.x;
    const int q = t & 31;        // output-quad: o = 4q+i
    const int r = t >> 5;        // point-octet: p = 8r+pp
    const int q4 = q << 2, rr = r << 3;

    // prefetch layer-0 W into registers
    float4 wstage[8];
    {
        const float4* wg = (const float4*)(WtG + (size_t)(bin * NHID) * WID * WID);
#pragma unroll
        for (int it = 0; it < 8; ++it) wstage[it] = wg[it * TMLP + t];
    }

    // tile metadata + small params
    if (t < PTILE) {
        int idx = tile * PTILE + t;
        if (idx < cnt) {
            int pid = tasks[start + idx];
            lTid[t] = pid;
            float xx = x[pid];
            float u = (xx - centers[bin]) * (1.0f / scales[bin]);
            lU[t] = u;
            float rs = coswin(u);
            int other = bin + (u > 0.0f ? 1 : -1);
            float ro = 0.0f;
            if (other >= 0 && other < NS)
                ro = coswin((xx - centers[other]) * (1.0f / scales[other]));
            lWgt[t] = rs / (rs + ro + 1e-8f);
        } else { lTid[t] = -1; lU[t] = 0.0f; lWgt[t] = 0.0f; }
    } else if (t < 256) { lWin[t - 128]  = W_in[bin * WID + (t - 128)]; }
    else if (t < 384)   { lBinp[t - 256] = b_in[bin * WID + (t - 256)]; }
    else                { lWo[t - 384]   = W_out[bin * WID + (t - 384)]; }
    __syncthreads();

    // input layer: h0[o][p] = tanh(u[p]*Win[o] + bin[o])
    {
        const int cb = rr ^ ((q & 3) << 3);
        float uv[8];
#pragma unroll
        for (int pp = 0; pp < 8; ++pp) uv[pp] = lU[rr + pp];
#pragma unroll
        for (int i = 0; i < 4; ++i) {
            float wv = lWin[q4 + i], bv = lBinp[q4 + i];
            float4 v0, v1;
            v0.x = tanh_fast(fmaf(uv[0], wv, bv));
            v0.y = tanh_fast(fmaf(uv[1], wv, bv));
            v0.z = tanh_fast(fmaf(uv[2], wv, bv));
            v0.w = tanh_fast(fmaf(uv[3], wv, bv));
            v1.x = tanh_fast(fmaf(uv[4], wv, bv));
            v1.y = tanh_fast(fmaf(uv[5], wv, bv));
            v1.z = tanh_fast(fmaf(uv[6], wv, bv));
            v1.w = tanh_fast(fmaf(uv[7], wv, bv));
            *(float4*)&lH[(q4 + i) * WID + cb] = v0;
            *(float4*)&lH[(q4 + i) * WID + cb + 4] = v1;
        }
    }
    __syncthreads();

    // hidden layers
    for (int l = 0; l < NHID; ++l) {
        {   // commit staged W to LDS (contiguous b128 stores, conflict-free)
            float4* lw4 = (float4*)lWt;
#pragma unroll
            for (int it = 0; it < 8; ++it) lw4[it * TMLP + t] = wstage[it];
        }
        if (t < WID) lBb[t] = b_hid[(bin * NHID + l) * WID + t];
        __syncthreads();
        if (l + 1 < NHID) {  // prefetch next layer during compute
            const float4* wg = (const float4*)(WtG + (size_t)(bin * NHID + l + 1) * WID * WID);
#pragma unroll
            for (int it = 0; it < 8; ++it) wstage[it] = wg[it * TMLP + t];
        }

        float acc[4][8];
#pragma unroll
        for (int i = 0; i < 4; ++i) {
            float bv = lBb[q4 + i];
#pragma unroll
            for (int pp = 0; pp < 8; ++pp) acc[i][pp] = bv;
        }

#pragma unroll 4
        for (int kc = 0; kc < 32; ++kc) {
            const int cb = rr ^ ((kc & 3) << 3);
            const float* hrow = &lH[(kc << 2) * WID + cb];
            const float* wrow = &lWt[(kc << 2) * WID + q4];
#pragma unroll
            for (int j = 0; j < 4; ++j) {
                float4 wv = *(const float4*)(wrow + j * WID);
                float4 h0 = *(const float4*)(hrow + j * WID);
                float4 h1 = *(const float4*)(hrow + j * WID + 4);
                const float wa[4] = {wv.x, wv.y, wv.z, wv.w};
                const float ha[8] = {h0.x, h0.y, h0.z, h0.w, h1.x, h1.y, h1.z, h1.w};
#pragma unroll
                for (int i = 0; i < 4; ++i)
#pragma unroll
                    for (int pp = 0; pp < 8; ++pp)
                        acc[i][pp] = fmaf(wa[i], ha[pp], acc[i][pp]);
            }
        }
        __syncthreads();  // all lWt/lH reads of this layer done
        {
            const int cb = rr ^ ((q & 3) << 3);
#pragma unroll
            for (int i = 0; i < 4; ++i) {
                float4 v0, v1;
                v0.x = tanh_fast(acc[i][0]);
                v0.y = tanh_fast(acc[i][1]);
                v0.z = tanh_fast(acc[i][2]);
                v0.w = tanh_fast(acc[i][3]);
                v1.x = tanh_fast(acc[i][4]);
                v1.y = tanh_fast(acc[i][5]);
                v1.z = tanh_fast(acc[i][6]);
                v1.w = tanh_fast(acc[i][7]);
                *(float4*)&lH[(q4 + i) * WID + cb] = v0;
                *(float4*)&lH[(q4 + i) * WID + cb + 4] = v1;
            }
        }
        __syncthreads();
    }

    // output layer: out[p] = sum_k Wo[k]*h[k][p] + bo;  4 partial groups over k
    {
        const int p = t & (PTILE - 1);
        const int g = t >> 7;
        float part = 0.0f;
#pragma unroll 8
        for (int n = 0; n < 32; ++n) {
            const int k = (g << 5) + n;
            const int col = p ^ (((k >> 2) & 3) << 3);
            part = fmaf(lH[k * WID + col], lWo[k], part);
        }
        lRed[(g << 7) + p] = part;
    }
    __syncthreads();
    if (t < PTILE) {
        float v = ((lRed[t] + lRed[PTILE + t]) + (lRed[2 * PTILE + t] + lRed[3 * PTILE + t]))
                  + b_out[bin];
        int pid = lTid[t];
        if (pid >= 0) atomicAdd(out + pid, lWgt[t] * v);  // <=2 addends per point: deterministic
    }
}

extern "C" void kernel_launch(void* const* d_in, const int* in_sizes, int n_in,
                              void* d_out, int out_size, void* d_ws, size_t ws_size,
                              hipStream_t stream) {
    const float* x       = (const float*)d_in[0];
    const float* W_in    = (const float*)d_in[1];
    const float* b_in    = (const float*)d_in[2];
    const float* W_hid   = (const float*)d_in[3];
    const float* b_hid   = (const float*)d_in[4];
    const float* W_out   = (const float*)d_in[5];
    const float* b_out   = (const float*)d_in[6];
    const float* centers = (const float*)d_in[7];
    const float* scales  = (const float*)d_in[8];
    float* out = (float*)d_out;

    char* ws = (char*)d_ws;
    int* counts  = (int*)(ws);
    int* cursors = (int*)(ws + 128);
    int* offsets = (int*)(ws + 256);
    int* tasks   = (int*)(ws + TASKS_OFF);
    float* WtG   = (float*)(ws + WT_OFF);

    hipMemsetAsync(d_out, 0, (size_t)out_size * sizeof(float), stream);
    hipMemsetAsync(ws, 0, 256, stream);

    k_transpose<<<dim3(96 * 16), dim3(32, 8), 0, stream>>>(W_hid, WtG);
    k_count<<<dim3(NPTS / 256), dim3(256), 0, stream>>>(x, counts, NPTS);
    k_scan<<<1, 32, 0, stream>>>(counts, offsets, cursors);
    k_scatter<<<dim3(NPTS / 256), dim3(256), 0, stream>>>(x, cursors, tasks, NPTS);
    k_mlp<<<dim3(TPB, NS), dim3(TMLP), 0, stream>>>(x, W_in, b_in, b_hid, W_out, b_out,
                                                    centers, scales, counts, offsets, tasks,
                                                    WtG, out);
}

// Round 2
// 740.296 us; speedup vs baseline: 1.2097x; 1.2097x over previous
//
#include <hip/hip_runtime.h>

#define NS 32
#define WID 128
#define NHID 3
#define NPTS 262144
#define PTILE 64      // points per block
#define TMLP 512      // 8 waves: wave w owns output neurons [16w, 16w+16)
#define TPB 272       // tiles per bin: capacity 17408 tasks/bin (expected ~16384 +- ~120)

#define TASKS_OFF 512
#define WT_OFF (TASKS_OFF + 2 * NPTS * 4)

__device__ __forceinline__ float tanh_fast(float v) {
    // tanh(v) = 1 - 2/(exp2(v*2*log2e)+1); monotone, saturates correctly, ~1e-6 abs err
    float a = v * 2.8853900817779268f;
    float e; asm("v_exp_f32 %0, %1" : "=v"(e) : "v"(a));
    float d = e + 1.0f;
    float r; asm("v_rcp_f32 %0, %1" : "=v"(r) : "v"(d));
    return fmaf(-2.0f, r, 1.0f);
}

__device__ __forceinline__ float coswin(float u) {
    // cos(pi/2 * u)^2 for |u|<1 else 0; v_cos takes revolutions: cos(2*pi*(u/4))
    if (fabsf(u) >= 1.0f) return 0.0f;
    float rev = u * 0.25f;
    float c; asm("v_cos_f32 %0, %1" : "=v"(c) : "v"(rev));
    return c * c;
}

// ---------------- bucketing ----------------

__global__ void k_count(const float* __restrict__ x, int* __restrict__ counts, int n) {
    __shared__ int loc[NS];
    int t = threadIdx.x;
    if (t < NS) loc[t] = 0;
    __syncthreads();
    int i = blockIdx.x * blockDim.x + t;
    if (i < n) {
        float tt = x[i] * 32.0f;
        int j = (int)floorf(tt); j = min(max(j, 0), 31);
        atomicAdd(&loc[j], 1);
        float u = tt - (float)j - 0.5f;
        int nb = (u > 0.0f) ? j + 1 : j - 1;
        if (u != 0.0f && nb >= 0 && nb < NS) atomicAdd(&loc[nb], 1);
    }
    __syncthreads();
    if (t < NS) atomicAdd(&counts[t], loc[t]);
}

__global__ void k_scan(const int* __restrict__ counts, int* __restrict__ offsets,
                       int* __restrict__ cursors) {
    if (threadIdx.x == 0) {
        int acc = 0;
        for (int s = 0; s < NS; ++s) { offsets[s] = acc; cursors[s] = acc; acc += counts[s]; }
    }
}

__global__ void k_scatter(const float* __restrict__ x, int* __restrict__ cursors,
                          int* __restrict__ tasks, int n) {
    __shared__ int loc[NS];
    __shared__ int base[NS];
    int t = threadIdx.x;
    if (t < NS) loc[t] = 0;
    __syncthreads();
    int i = blockIdx.x * blockDim.x + t;
    int j = -1, nb = -1, sj = 0, snb = 0;
    if (i < n) {
        float tt = x[i] * 32.0f;
        j = min(max((int)floorf(tt), 0), 31);
        sj = atomicAdd(&loc[j], 1);
        float u = tt - (float)j - 0.5f;
        int nb2 = (u > 0.0f) ? j + 1 : j - 1;
        if (u != 0.0f && nb2 >= 0 && nb2 < NS) { nb = nb2; snb = atomicAdd(&loc[nb], 1); }
    }
    __syncthreads();
    if (t < NS) base[t] = atomicAdd(&cursors[t], loc[t]);
    __syncthreads();
    if (i < n) {
        tasks[base[j] + sj] = i;
        if (nb >= 0) tasks[base[nb] + snb] = i;
    }
}

// ---------------- W_hid transpose: Wt[s][l][k][o] = W[s][l][o][k] ----------------

__global__ void k_transpose(const float* __restrict__ Wh, float* __restrict__ Wt) {
    __shared__ float tile[32][33];
    int m  = blockIdx.x >> 4;        // matrix 0..95
    int tr = (blockIdx.x >> 2) & 3;  // o-tile
    int tc = blockIdx.x & 3;         // k-tile
    const float* src = Wh + (size_t)m * 16384;
    float* dst = Wt + (size_t)m * 16384;
    int lx = threadIdx.x, ly = threadIdx.y;  // 32 x 8
    for (int yy = ly; yy < 32; yy += 8)
        tile[yy][lx] = src[(tr * 32 + yy) * WID + tc * 32 + lx];
    __syncthreads();
    for (int yy = ly; yy < 32; yy += 8)
        dst[(tc * 32 + yy) * WID + tr * 32 + lx] = tile[lx][yy];
}

// ---------------- main fused MLP: SGPR weights, per-lane point, LDS h ping-pong ----

__global__ __launch_bounds__(TMLP, 4) void k_mlp(
    const float* __restrict__ x, const float* __restrict__ W_in, const float* __restrict__ b_in,
    const float* __restrict__ b_hid, const float* __restrict__ W_out, const float* __restrict__ b_out,
    const float* __restrict__ centers, const float* __restrict__ scales,
    const int* __restrict__ counts, const int* __restrict__ offsets, const int* __restrict__ tasks,
    const float* __restrict__ WtG, float* __restrict__ out) {

    const int bin = blockIdx.y;
    const int tile = blockIdx.x;
    const int cnt = counts[bin];
    if (tile * PTILE >= cnt) return;
    const int start = offsets[bin];

    // h layout: [kk=k/2][p][2] floats -> linear b64 per (kk, lane p), conflict-free
    __shared__ __align__(16) float hA[64 * PTILE * 2];   // 32 KB
    __shared__ __align__(16) float hB[64 * PTILE * 2];   // 32 KB
    __shared__ float lU[PTILE], lWgt[PTILE];
    __shared__ int lTid[PTILE];
    __shared__ float lRed[8 * PTILE];

    const int t = threadIdx.x;
    const int p = t & 63;                                   // lane = point
    const int w = __builtin_amdgcn_readfirstlane(t >> 6);   // wave id 0..7 (uniform)
    const int w16 = w << 4;

    if (t < PTILE) {
        int idx = tile * PTILE + t;
        if (idx < cnt) {
            int pid = tasks[start + idx];
            lTid[t] = pid;
            float xx = x[pid];
            float u = (xx - centers[bin]) * (1.0f / scales[bin]);
            lU[t] = u;
            float rs = coswin(u);
            int other = bin + (u > 0.0f ? 1 : -1);
            float ro = 0.0f;
            if (other >= 0 && other < NS)
                ro = coswin((xx - centers[other]) * (1.0f / scales[other]));
            lWgt[t] = rs / (rs + ro + 1e-8f);
        } else { lTid[t] = -1; lU[t] = 0.0f; lWgt[t] = 0.0f; }
    }
    __syncthreads();

    // ---- input layer: h0[o] = tanh(u * Win[o] + bin[o]), o in wave's 16-chunk ----
    const float u = lU[p];
    {
        const float* Win = W_in + bin * WID + w16;   // uniform -> s_load
        const float* Bin = b_in + bin * WID + w16;
        float hv[16];
#pragma unroll
        for (int i = 0; i < 16; ++i) hv[i] = tanh_fast(fmaf(u, Win[i], Bin[i]));
#pragma unroll
        for (int j = 0; j < 8; ++j) {
            float2 v; v.x = hv[2 * j]; v.y = hv[2 * j + 1];
            *(float2*)&hA[(((w << 3) + j) * PTILE + p) * 2] = v;
        }
    }
    __syncthreads();

    // ---- hidden layers: acc[o] += W[k][o] * h[k], W from SGPRs, h via ds_read_b64 ----
    float* cur = hA;
    float* nxt = hB;
    for (int l = 0; l < NHID; ++l) {
        const float* wrow = WtG + (size_t)(bin * NHID + l) * WID * WID + w16;  // uniform
        const float* bh = b_hid + (bin * NHID + l) * WID + w16;                // uniform
        float acc[16];
#pragma unroll
        for (int i = 0; i < 16; ++i) acc[i] = bh[i];

#pragma unroll 2
        for (int kk = 0; kk < 64; ++kk) {
            float2 h = *(const float2*)&cur[(kk * PTILE + p) * 2];
            const float* w0 = wrow + (2 * kk) * WID;       // uniform row k=2kk
            const float* w1 = w0 + WID;                    // uniform row k=2kk+1
#pragma unroll
            for (int i = 0; i < 16; ++i) acc[i] = fmaf(w0[i], h.x, acc[i]);
#pragma unroll
            for (int i = 0; i < 16; ++i) acc[i] = fmaf(w1[i], h.y, acc[i]);
        }

#pragma unroll
        for (int j = 0; j < 8; ++j) {
            float2 v; v.x = tanh_fast(acc[2 * j]); v.y = tanh_fast(acc[2 * j + 1]);
            *(float2*)&nxt[(((w << 3) + j) * PTILE + p) * 2] = v;
        }
        __syncthreads();
        float* tmp = cur; cur = nxt; nxt = tmp;
    }

    // ---- output layer: k-split across waves, LDS reduce ----
    {
        const float* Wo = W_out + bin * WID + w16;   // uniform
        float part = 0.0f;
#pragma unroll
        for (int j = 0; j < 8; ++j) {
            float2 h = *(const float2*)&cur[(((w << 3) + j) * PTILE + p) * 2];
            part = fmaf(Wo[2 * j], h.x, part);
            part = fmaf(Wo[2 * j + 1], h.y, part);
        }
        lRed[w * PTILE + p] = part;
    }
    __syncthreads();
    if (t < PTILE) {
        float v = ((lRed[t] + lRed[PTILE + t]) + (lRed[2 * PTILE + t] + lRed[3 * PTILE + t]))
                + ((lRed[4 * PTILE + t] + lRed[5 * PTILE + t]) + (lRed[6 * PTILE + t] + lRed[7 * PTILE + t]))
                + b_out[bin];
        int pid = lTid[t];
        if (pid >= 0) atomicAdd(out + pid, lWgt[t] * v);  // <=2 addends per point: deterministic
    }
}

extern "C" void kernel_launch(void* const* d_in, const int* in_sizes, int n_in,
                              void* d_out, int out_size, void* d_ws, size_t ws_size,
                              hipStream_t stream) {
    const float* x       = (const float*)d_in[0];
    const float* W_in    = (const float*)d_in[1];
    const float* b_in    = (const float*)d_in[2];
    const float* W_hid   = (const float*)d_in[3];
    const float* b_hid   = (const float*)d_in[4];
    const float* W_out   = (const float*)d_in[5];
    const float* b_out   = (const float*)d_in[6];
    const float* centers = (const float*)d_in[7];
    const float* scales  = (const float*)d_in[8];
    float* out = (float*)d_out;

    char* ws = (char*)d_ws;
    int* counts  = (int*)(ws);
    int* cursors = (int*)(ws + 128);
    int* offsets = (int*)(ws + 256);
    int* tasks   = (int*)(ws + TASKS_OFF);
    float* WtG   = (float*)(ws + WT_OFF);

    hipMemsetAsync(d_out, 0, (size_t)out_size * sizeof(float), stream);
    hipMemsetAsync(ws, 0, 256, stream);

    k_transpose<<<dim3(96 * 16), dim3(32, 8), 0, stream>>>(W_hid, WtG);
    k_count<<<dim3(NPTS / 256), dim3(256), 0, stream>>>(x, counts, NPTS);
    k_scan<<<1, 32, 0, stream>>>(counts, offsets, cursors);
    k_scatter<<<dim3(NPTS / 256), dim3(256), 0, stream>>>(x, cursors, tasks, NPTS);
    k_mlp<<<dim3(TPB, NS), dim3(TMLP), 0, stream>>>(x, W_in, b_in, b_hid, W_out, b_out,
                                                    centers, scales, counts, offsets, tasks,
                                                    WtG, out);
}

// Round 3
// 176.673 us; speedup vs baseline: 5.0689x; 4.1902x over previous
//
#include <hip/hip_runtime.h>

#define NS 32
#define WID 128
#define NHID 3
#define NPTS 262144
#define PTILE 128     // points per block (16 per wave)
#define TMLP 512      // 8 waves
#define TPB 136       // tiles per bin: capacity 17408 tasks/bin (proven in R1)

#define TASKS_OFF 512
#define WF_OFF (TASKS_OFF + 2 * NPTS * 4)

typedef _Float16 f16x4 __attribute__((ext_vector_type(4)));
typedef _Float16 f16x8 __attribute__((ext_vector_type(8)));
typedef float f32x4 __attribute__((ext_vector_type(4)));

union U4H8 { uint4 u; f16x8 h; };

__device__ __forceinline__ float tanh_fast(float v) {
    float a = v * 2.8853900817779268f;
    float e; asm("v_exp_f32 %0, %1" : "=v"(e) : "v"(a));
    float d = e + 1.0f;
    float r; asm("v_rcp_f32 %0, %1" : "=v"(r) : "v"(d));
    return fmaf(-2.0f, r, 1.0f);
}

__device__ __forceinline__ float coswin(float u) {
    if (fabsf(u) >= 1.0f) return 0.0f;
    float rev = u * 0.25f;
    float c; asm("v_cos_f32 %0, %1" : "=v"(c) : "v"(rev));
    return c * c;
}

// ---------------- bucketing (proven R0/R1) ----------------

__global__ void k_count(const float* __restrict__ x, int* __restrict__ counts, int n) {
    __shared__ int loc[NS];
    int t = threadIdx.x;
    if (t < NS) loc[t] = 0;
    __syncthreads();
    int i = blockIdx.x * blockDim.x + t;
    if (i < n) {
        float tt = x[i] * 32.0f;
        int j = (int)floorf(tt); j = min(max(j, 0), 31);
        atomicAdd(&loc[j], 1);
        float u = tt - (float)j - 0.5f;
        int nb = (u > 0.0f) ? j + 1 : j - 1;
        if (u != 0.0f && nb >= 0 && nb < NS) atomicAdd(&loc[nb], 1);
    }
    __syncthreads();
    if (t < NS) atomicAdd(&counts[t], loc[t]);
}

__global__ void k_scan(const int* __restrict__ counts, int* __restrict__ offsets,
                       int* __restrict__ cursors) {
    if (threadIdx.x == 0) {
        int acc = 0;
        for (int s = 0; s < NS; ++s) { offsets[s] = acc; cursors[s] = acc; acc += counts[s]; }
    }
}

__global__ void k_scatter(const float* __restrict__ x, int* __restrict__ cursors,
                          int* __restrict__ tasks, int n) {
    __shared__ int loc[NS];
    __shared__ int base[NS];
    int t = threadIdx.x;
    if (t < NS) loc[t] = 0;
    __syncthreads();
    int i = blockIdx.x * blockDim.x + t;
    int j = -1, nb = -1, sj = 0, snb = 0;
    if (i < n) {
        float tt = x[i] * 32.0f;
        j = min(max((int)floorf(tt), 0), 31);
        sj = atomicAdd(&loc[j], 1);
        float u = tt - (float)j - 0.5f;
        int nb2 = (u > 0.0f) ? j + 1 : j - 1;
        if (u != 0.0f && nb2 >= 0 && nb2 < NS) { nb = nb2; snb = atomicAdd(&loc[nb], 1); }
    }
    __syncthreads();
    if (t < NS) base[t] = atomicAdd(&cursors[t], loc[t]);
    __syncthreads();
    if (i < n) {
        tasks[base[j] + sj] = i;
        if (nb >= 0) tasks[base[nb] + snb] = i;
    }
}

// ---------------- W fragment pre-pack (fp16, MFMA B-operand order) ----------------
// Wf[bin][l][t8][s][lane][e]: e=0..7 -> k = 32s + 4*(lane>>4) + (e&3) + 16*(e>>2),
//                              o = 16*t8 + (lane&15); value = W_hid[bin][l][o][k]

__global__ void k_prepw(const float* __restrict__ Wh, uint4* __restrict__ WfU4) {
    int tid = blockIdx.x * blockDim.x + threadIdx.x;   // 196608 threads
    if (tid >= 32 * 3 * 8 * 4 * 64) return;
    int lane = tid & 63;
    int s    = (tid >> 6) & 3;
    int t8   = (tid >> 8) & 7;
    int v    = tid >> 11;            // bin*3 + l, 0..95
    int o    = 16 * t8 + (lane & 15);
    const float* src = Wh + ((size_t)v * 128 + o) * 128;
    unsigned short b[8];
#pragma unroll
    for (int e = 0; e < 8; ++e) {
        int k = 32 * s + 4 * (lane >> 4) + (e & 3) + 16 * (e >> 2);
        _Float16 hv = (_Float16)src[k];
        b[e] = *(unsigned short*)&hv;
    }
    uint4 outv;
    outv.x = (unsigned)b[0] | ((unsigned)b[1] << 16);
    outv.y = (unsigned)b[2] | ((unsigned)b[3] << 16);
    outv.z = (unsigned)b[4] | ((unsigned)b[5] << 16);
    outv.w = (unsigned)b[6] | ((unsigned)b[7] << 16);
    WfU4[((size_t)(v * 8 + t8) * 4 + s) * 64 + lane] = outv;
}

// ---------------- main fused MLP: fp16 MFMA, wave-private state ----------------

__global__ __launch_bounds__(TMLP, 4) void k_mlp(
    const float* __restrict__ x, const float* __restrict__ W_in, const float* __restrict__ b_in,
    const float* __restrict__ b_hid, const float* __restrict__ W_out, const float* __restrict__ b_out,
    const float* __restrict__ centers, const float* __restrict__ scales,
    const int* __restrict__ counts, const int* __restrict__ offsets, const int* __restrict__ tasks,
    const uint4* __restrict__ WfU4, float* __restrict__ out) {

    const int bin = blockIdx.y;
    const int tile = blockIdx.x;
    const int cnt = counts[bin];
    if (tile * PTILE >= cnt) return;
    const int start = offsets[bin];

    // per-wave H^T[k=0..127][p=0..15] fp16, row-major 32B/row (4KB per wave)
    __shared__ __align__(256) _Float16 HT[8][2048];
    __shared__ float lU[PTILE], lWgt[PTILE];
    __shared__ int lTid[PTILE];

    const int t = threadIdx.x;
    const int lane = t & 63;
    const int l15 = t & 15;
    const int g = (t >> 4) & 3;       // 4-lane-group id: this lane covers points 4g..4g+3
    const int w = t >> 6;             // wave id 0..7: points w*16..w*16+15

    // tile metadata (window weights) — proven R1 code
    if (t < PTILE) {
        int idx = tile * PTILE + t;
        if (idx < cnt) {
            int pid = tasks[start + idx];
            lTid[t] = pid;
            float xx = x[pid];
            float u = (xx - centers[bin]) * (1.0f / scales[bin]);
            lU[t] = u;
            float rs = coswin(u);
            int other = bin + (u > 0.0f ? 1 : -1);
            float ro = 0.0f;
            if (other >= 0 && other < NS)
                ro = coswin((xx - centers[other]) * (1.0f / scales[other]));
            lWgt[t] = rs / (rs + ro + 1e-8f);
        } else { lTid[t] = -1; lU[t] = 0.0f; lWgt[t] = 0.0f; }
    }
    __syncthreads();

    // ---- input layer: HT[o][p] = tanh(u[p]*Win[o]+bin[o]) (fp32 compute, fp16 store)
    {
        float4 u4 = *(const float4*)&lU[w * 16 + 4 * g];
        const float* Win = W_in + bin * WID;
        const float* Bi  = b_in + bin * WID;
#pragma unroll
        for (int t8 = 0; t8 < 8; ++t8) {
            int o = 16 * t8 + l15;
            float wv = Win[o], bv = Bi[o];
            f16x4 hv;
            hv[0] = (_Float16)tanh_fast(fmaf(u4.x, wv, bv));
            hv[1] = (_Float16)tanh_fast(fmaf(u4.y, wv, bv));
            hv[2] = (_Float16)tanh_fast(fmaf(u4.z, wv, bv));
            hv[3] = (_Float16)tanh_fast(fmaf(u4.w, wv, bv));
            *(f16x4*)&HT[w][o * 16 + 4 * g] = hv;
        }
    }
    // NOTE: no barrier needed — HT is wave-private, LDS ops are in-order per wave.

    const unsigned htaddr = (unsigned)(size_t)&HT[w][0] + lane * 8;
    const uint4* wfbase = WfU4 + (size_t)(bin * 3) * 32 * 64;
    float part0 = 0.f, part1 = 0.f, part2 = 0.f, part3 = 0.f;

#pragma unroll
    for (int lyr = 0; lyr < NHID; ++lyr) {
        // A-fragments for all 4 k-steps via HW transpose-read; waitcnt bundled in-block
        f16x4 a0, a1, a2, a3, a4, a5, a6, a7;
        asm volatile(
            "ds_read_b64_tr_b16 %0, %8 offset:0\n\t"
            "ds_read_b64_tr_b16 %1, %8 offset:512\n\t"
            "ds_read_b64_tr_b16 %2, %8 offset:1024\n\t"
            "ds_read_b64_tr_b16 %3, %8 offset:1536\n\t"
            "ds_read_b64_tr_b16 %4, %8 offset:2048\n\t"
            "ds_read_b64_tr_b16 %5, %8 offset:2560\n\t"
            "ds_read_b64_tr_b16 %6, %8 offset:3072\n\t"
            "ds_read_b64_tr_b16 %7, %8 offset:3584\n\t"
            "s_waitcnt lgkmcnt(0)"
            : "=v"(a0), "=v"(a1), "=v"(a2), "=v"(a3),
              "=v"(a4), "=v"(a5), "=v"(a6), "=v"(a7)
            : "v"(htaddr) : "memory");
        f16x8 A[4];
        A[0] = __builtin_shufflevector(a0, a1, 0, 1, 2, 3, 4, 5, 6, 7);
        A[1] = __builtin_shufflevector(a2, a3, 0, 1, 2, 3, 4, 5, 6, 7);
        A[2] = __builtin_shufflevector(a4, a5, 0, 1, 2, 3, 4, 5, 6, 7);
        A[3] = __builtin_shufflevector(a6, a7, 0, 1, 2, 3, 4, 5, 6, 7);

        f32x4 acc[8];
#pragma unroll
        for (int t8 = 0; t8 < 8; ++t8) acc[t8] = (f32x4){0.f, 0.f, 0.f, 0.f};

        const uint4* wf = wfbase + (size_t)lyr * 32 * 64;
#pragma unroll
        for (int s = 0; s < 4; ++s) {
#pragma unroll
            for (int t8 = 0; t8 < 8; ++t8) {
                U4H8 bw; bw.u = wf[(size_t)(t8 * 4 + s) * 64 + lane];
                acc[t8] = __builtin_amdgcn_mfma_f32_16x16x32_f16(A[s], bw.h, acc[t8], 0, 0, 0);
            }
        }

        const float* bh = b_hid + (size_t)(bin * NHID + lyr) * WID;
        if (lyr < NHID - 1) {
#pragma unroll
            for (int t8 = 0; t8 < 8; ++t8) {
                int o = 16 * t8 + l15;
                float bv = bh[o];
                f16x4 hv;
                hv[0] = (_Float16)tanh_fast(acc[t8][0] + bv);
                hv[1] = (_Float16)tanh_fast(acc[t8][1] + bv);
                hv[2] = (_Float16)tanh_fast(acc[t8][2] + bv);
                hv[3] = (_Float16)tanh_fast(acc[t8][3] + bv);
                *(f16x4*)&HT[w][o * 16 + 4 * g] = hv;
            }
        } else {
            const float* Wo = W_out + bin * WID;
#pragma unroll
            for (int t8 = 0; t8 < 8; ++t8) {
                int o = 16 * t8 + l15;
                float bv = bh[o], wv = Wo[o];
                part0 = fmaf(wv, tanh_fast(acc[t8][0] + bv), part0);
                part1 = fmaf(wv, tanh_fast(acc[t8][1] + bv), part1);
                part2 = fmaf(wv, tanh_fast(acc[t8][2] + bv), part2);
                part3 = fmaf(wv, tanh_fast(acc[t8][3] + bv), part3);
            }
        }
    }

    // reduce over the 16 lanes (l15 bits) of each 4-lane point-group
#pragma unroll
    for (int m = 1; m < 16; m <<= 1) {
        part0 += __shfl_xor(part0, m);
        part1 += __shfl_xor(part1, m);
        part2 += __shfl_xor(part2, m);
        part3 += __shfl_xor(part3, m);
    }
    if (l15 < 4) {
        float v = (l15 == 0) ? part0 : (l15 == 1) ? part1 : (l15 == 2) ? part2 : part3;
        v += b_out[bin];
        int ploc = w * 16 + 4 * g + l15;
        int pid = lTid[ploc];
        if (pid >= 0) atomicAdd(out + pid, lWgt[ploc] * v);  // <=2 addends: deterministic
    }
}

extern "C" void kernel_launch(void* const* d_in, const int* in_sizes, int n_in,
                              void* d_out, int out_size, void* d_ws, size_t ws_size,
                              hipStream_t stream) {
    const float* x       = (const float*)d_in[0];
    const float* W_in    = (const float*)d_in[1];
    const float* b_in    = (const float*)d_in[2];
    const float* W_hid   = (const float*)d_in[3];
    const float* b_hid   = (const float*)d_in[4];
    const float* W_out   = (const float*)d_in[5];
    const float* b_out   = (const float*)d_in[6];
    const float* centers = (const float*)d_in[7];
    const float* scales  = (const float*)d_in[8];
    float* out = (float*)d_out;

    char* ws = (char*)d_ws;
    int* counts  = (int*)(ws);
    int* cursors = (int*)(ws + 128);
    int* offsets = (int*)(ws + 256);
    int* tasks   = (int*)(ws + TASKS_OFF);
    uint4* WfU4  = (uint4*)(ws + WF_OFF);

    hipMemsetAsync(d_out, 0, (size_t)out_size * sizeof(float), stream);
    hipMemsetAsync(ws, 0, 256, stream);

    k_prepw<<<dim3(768), dim3(256), 0, stream>>>(W_hid, WfU4);
    k_count<<<dim3(NPTS / 256), dim3(256), 0, stream>>>(x, counts, NPTS);
    k_scan<<<1, 32, 0, stream>>>(counts, offsets, cursors);
    k_scatter<<<dim3(NPTS / 256), dim3(256), 0, stream>>>(x, cursors, tasks, NPTS);
    k_mlp<<<dim3(TPB, NS), dim3(TMLP), 0, stream>>>(x, W_in, b_in, b_hid, W_out, b_out,
                                                    centers, scales, counts, offsets, tasks,
                                                    WfU4, out);
}

// Round 4
// 147.406 us; speedup vs baseline: 6.0753x; 1.1985x over previous
//
#include <hip/hip_runtime.h>

#define NS 32
#define WID 128
#define NHID 3
#define NPTS 262144
#define PTILE 256     // points per block (32 per wave)
#define TMLP 512      // 8 waves
#define TPB 68        // tiles per bin: capacity 17408 tasks/bin (proven R1-R3)

#define TASKS_OFF 512
#define WF_OFF (TASKS_OFF + 2 * NPTS * 4)
#define TANH_C 2.8853900817779268f   // 2*log2(e)

typedef _Float16 f16x4 __attribute__((ext_vector_type(4)));
typedef _Float16 f16x8 __attribute__((ext_vector_type(8)));
typedef float f32x4 __attribute__((ext_vector_type(4)));

union U4H8 { uint4 u; f16x8 h; };

__device__ __forceinline__ float tanh_fast(float v) {
    float a = v * TANH_C;
    float e; asm("v_exp_f32 %0, %1" : "=v"(e) : "v"(a));
    float d = e + 1.0f;
    float r; asm("v_rcp_f32 %0, %1" : "=v"(r) : "v"(d));
    return fmaf(-2.0f, r, 1.0f);
}

// input already pre-scaled by TANH_C (folded into Wf/bias)
__device__ __forceinline__ float tanh_pre(float a) {
    float e; asm("v_exp_f32 %0, %1" : "=v"(e) : "v"(a));
    float d = e + 1.0f;
    float r; asm("v_rcp_f32 %0, %1" : "=v"(r) : "v"(d));
    return fmaf(-2.0f, r, 1.0f);
}

__device__ __forceinline__ float coswin(float u) {
    if (fabsf(u) >= 1.0f) return 0.0f;
    float rev = u * 0.25f;
    float c; asm("v_cos_f32 %0, %1" : "=v"(c) : "v"(rev));
    return c * c;
}

// ---------------- bucketing (proven R0-R3) ----------------

__global__ void k_count(const float* __restrict__ x, int* __restrict__ counts, int n) {
    __shared__ int loc[NS];
    int t = threadIdx.x;
    if (t < NS) loc[t] = 0;
    __syncthreads();
    int i = blockIdx.x * blockDim.x + t;
    if (i < n) {
        float tt = x[i] * 32.0f;
        int j = (int)floorf(tt); j = min(max(j, 0), 31);
        atomicAdd(&loc[j], 1);
        float u = tt - (float)j - 0.5f;
        int nb = (u > 0.0f) ? j + 1 : j - 1;
        if (u != 0.0f && nb >= 0 && nb < NS) atomicAdd(&loc[nb], 1);
    }
    __syncthreads();
    if (t < NS) atomicAdd(&counts[t], loc[t]);
}

__global__ void k_scan(const int* __restrict__ counts, int* __restrict__ offsets,
                       int* __restrict__ cursors) {
    if (threadIdx.x == 0) {
        int acc = 0;
        for (int s = 0; s < NS; ++s) { offsets[s] = acc; cursors[s] = acc; acc += counts[s]; }
    }
}

__global__ void k_scatter(const float* __restrict__ x, int* __restrict__ cursors,
                          int* __restrict__ tasks, int n) {
    __shared__ int loc[NS];
    __shared__ int base[NS];
    int t = threadIdx.x;
    if (t < NS) loc[t] = 0;
    __syncthreads();
    int i = blockIdx.x * blockDim.x + t;
    int j = -1, nb = -1, sj = 0, snb = 0;
    if (i < n) {
        float tt = x[i] * 32.0f;
        j = min(max((int)floorf(tt), 0), 31);
        sj = atomicAdd(&loc[j], 1);
        float u = tt - (float)j - 0.5f;
        int nb2 = (u > 0.0f) ? j + 1 : j - 1;
        if (u != 0.0f && nb2 >= 0 && nb2 < NS) { nb = nb2; snb = atomicAdd(&loc[nb], 1); }
    }
    __syncthreads();
    if (t < NS) base[t] = atomicAdd(&cursors[t], loc[t]);
    __syncthreads();
    if (i < n) {
        tasks[base[j] + sj] = i;
        if (nb >= 0) tasks[base[nb] + snb] = i;
    }
}

// ---------------- W fragment pre-pack (fp16, MFMA B order, pre-scaled) ----------
// Wf[v][s][t8][lane]: e=0..7 -> k = 32s + 4*(lane>>4) + (e&3) + 16*(e>>2),
//                     o = 16*t8 + (lane&15); value = TANH_C * W_hid[v][o][k]

__global__ void k_prepw(const float* __restrict__ Wh, uint4* __restrict__ WfU4) {
    int tid = blockIdx.x * blockDim.x + threadIdx.x;
    if (tid >= 32 * 3 * 4 * 8 * 64) return;
    int lane = tid & 63;
    int t8   = (tid >> 6) & 7;
    int s    = (tid >> 9) & 3;
    int v    = tid >> 11;            // bin*3 + l, 0..95
    int o    = 16 * t8 + (lane & 15);
    const float* src = Wh + ((size_t)v * 128 + o) * 128;
    unsigned short b[8];
#pragma unroll
    for (int e = 0; e < 8; ++e) {
        int k = 32 * s + 4 * (lane >> 4) + (e & 3) + 16 * (e >> 2);
        _Float16 hv = (_Float16)(src[k] * TANH_C);
        b[e] = *(unsigned short*)&hv;
    }
    uint4 outv;
    outv.x = (unsigned)b[0] | ((unsigned)b[1] << 16);
    outv.y = (unsigned)b[2] | ((unsigned)b[3] << 16);
    outv.z = (unsigned)b[4] | ((unsigned)b[5] << 16);
    outv.w = (unsigned)b[6] | ((unsigned)b[7] << 16);
    WfU4[((size_t)(v * 4 + s) * 8 + t8) * 64 + lane] = outv;
}

// ---------------- main fused MLP: fp16 MFMA, 32 points/wave ----------------

__global__ __launch_bounds__(TMLP, 4) void k_mlp(
    const float* __restrict__ x, const float* __restrict__ W_in, const float* __restrict__ b_in,
    const float* __restrict__ b_hid, const float* __restrict__ W_out, const float* __restrict__ b_out,
    const float* __restrict__ centers, const float* __restrict__ scales,
    const int* __restrict__ counts, const int* __restrict__ offsets, const int* __restrict__ tasks,
    const uint4* __restrict__ WfU4, float* __restrict__ out) {

    const int bin = blockIdx.y;
    const int tile = blockIdx.x;
    const int cnt = counts[bin];
    if (tile * PTILE >= cnt) return;
    const int start = offsets[bin];

    // per-wave H^T: 2 point-sets x [k=0..127][p=0..15] fp16 = 8KB/wave
    __shared__ __align__(256) _Float16 HT[8][4096];
    __shared__ float lU[PTILE], lWgt[PTILE];
    __shared__ int lTid[PTILE];

    const int t = threadIdx.x;
    const int lane = t & 63;
    const int l15 = t & 15;
    const int g = (t >> 4) & 3;       // lane covers points 4g..4g+3 of each set
    const int w = t >> 6;             // wave id: points w*32 .. w*32+31

    if (t < PTILE) {
        int idx = tile * PTILE + t;
        if (idx < cnt) {
            int pid = tasks[start + idx];
            lTid[t] = pid;
            float xx = x[pid];
            float u = (xx - centers[bin]) * (1.0f / scales[bin]);
            lU[t] = u;
            float rs = coswin(u);
            int other = bin + (u > 0.0f ? 1 : -1);
            float ro = 0.0f;
            if (other >= 0 && other < NS)
                ro = coswin((xx - centers[other]) * (1.0f / scales[other]));
            lWgt[t] = rs / (rs + ro + 1e-8f);
        } else { lTid[t] = -1; lU[t] = 0.0f; lWgt[t] = 0.0f; }
    }
    __syncthreads();

    // ---- input layer: both point-sets (fp32 compute, fp16 store) ----
    {
        float4 ua = *(const float4*)&lU[w * 32 + 4 * g];
        float4 ub = *(const float4*)&lU[w * 32 + 16 + 4 * g];
        const float* Win = W_in + bin * WID;
        const float* Bi  = b_in + bin * WID;
#pragma unroll
        for (int t8 = 0; t8 < 8; ++t8) {
            int o = 16 * t8 + l15;
            float wv = Win[o], bv = Bi[o];
            f16x4 h0, h1;
            h0[0] = (_Float16)tanh_fast(fmaf(ua.x, wv, bv));
            h0[1] = (_Float16)tanh_fast(fmaf(ua.y, wv, bv));
            h0[2] = (_Float16)tanh_fast(fmaf(ua.z, wv, bv));
            h0[3] = (_Float16)tanh_fast(fmaf(ua.w, wv, bv));
            h1[0] = (_Float16)tanh_fast(fmaf(ub.x, wv, bv));
            h1[1] = (_Float16)tanh_fast(fmaf(ub.y, wv, bv));
            h1[2] = (_Float16)tanh_fast(fmaf(ub.z, wv, bv));
            h1[3] = (_Float16)tanh_fast(fmaf(ub.w, wv, bv));
            *(f16x4*)&HT[w][o * 16 + 4 * g] = h0;
            *(f16x4*)&HT[w][2048 + o * 16 + 4 * g] = h1;
        }
    }
    // HT is wave-private; per-wave LDS ops are in-order -> no barrier needed.

    const unsigned htaddr = (unsigned)(size_t)&HT[w][0] + lane * 8;
    const uint4* wfbase = WfU4 + (size_t)(bin * NHID) * 32 * 64;
    float p0 = 0.f, p1 = 0.f, p2 = 0.f, p3 = 0.f;
    float q0 = 0.f, q1 = 0.f, q2 = 0.f, q3 = 0.f;

#pragma unroll
    for (int lyr = 0; lyr < NHID; ++lyr) {
        f32x4 acc0[8], acc1[8];
#pragma unroll
        for (int t8 = 0; t8 < 8; ++t8) {
            acc0[t8] = (f32x4){0.f, 0.f, 0.f, 0.f};
            acc1[t8] = (f32x4){0.f, 0.f, 0.f, 0.f};
        }
        const uint4* wfL = wfbase + (size_t)lyr * 32 * 64;
#pragma unroll
        for (int s = 0; s < 4; ++s) {
            unsigned ad0 = htaddr + s * 1024;
            unsigned ad1 = ad0 + 4096;
            f16x4 a0, a1, b0, b1;
            asm volatile(
                "ds_read_b64_tr_b16 %0, %4 offset:0\n\t"
                "ds_read_b64_tr_b16 %1, %4 offset:512\n\t"
                "ds_read_b64_tr_b16 %2, %5 offset:0\n\t"
                "ds_read_b64_tr_b16 %3, %5 offset:512\n\t"
                "s_waitcnt lgkmcnt(0)"
                : "=v"(a0), "=v"(a1), "=v"(b0), "=v"(b1)
                : "v"(ad0), "v"(ad1) : "memory");
            f16x8 A0 = __builtin_shufflevector(a0, a1, 0, 1, 2, 3, 4, 5, 6, 7);
            f16x8 A1 = __builtin_shufflevector(b0, b1, 0, 1, 2, 3, 4, 5, 6, 7);
            const uint4* wfs = wfL + s * 512 + lane;
#pragma unroll
            for (int t8 = 0; t8 < 8; ++t8) {
                U4H8 bw; bw.u = wfs[t8 * 64];
                acc0[t8] = __builtin_amdgcn_mfma_f32_16x16x32_f16(A0, bw.h, acc0[t8], 0, 0, 0);
                acc1[t8] = __builtin_amdgcn_mfma_f32_16x16x32_f16(A1, bw.h, acc1[t8], 0, 0, 0);
            }
        }

        const float* bh = b_hid + (size_t)(bin * NHID + lyr) * WID;
        if (lyr < NHID - 1) {
#pragma unroll
            for (int t8 = 0; t8 < 8; ++t8) {
                int o = 16 * t8 + l15;
                float bv = bh[o] * TANH_C;
                f16x4 h0, h1;
                h0[0] = (_Float16)tanh_pre(acc0[t8][0] + bv);
                h0[1] = (_Float16)tanh_pre(acc0[t8][1] + bv);
                h0[2] = (_Float16)tanh_pre(acc0[t8][2] + bv);
                h0[3] = (_Float16)tanh_pre(acc0[t8][3] + bv);
                h1[0] = (_Float16)tanh_pre(acc1[t8][0] + bv);
                h1[1] = (_Float16)tanh_pre(acc1[t8][1] + bv);
                h1[2] = (_Float16)tanh_pre(acc1[t8][2] + bv);
                h1[3] = (_Float16)tanh_pre(acc1[t8][3] + bv);
                *(f16x4*)&HT[w][o * 16 + 4 * g] = h0;
                *(f16x4*)&HT[w][2048 + o * 16 + 4 * g] = h1;
            }
        } else {
            const float* Wo = W_out + bin * WID;
#pragma unroll
            for (int t8 = 0; t8 < 8; ++t8) {
                int o = 16 * t8 + l15;
                float bv = bh[o] * TANH_C, wv = Wo[o];
                p0 = fmaf(wv, tanh_pre(acc0[t8][0] + bv), p0);
                p1 = fmaf(wv, tanh_pre(acc0[t8][1] + bv), p1);
                p2 = fmaf(wv, tanh_pre(acc0[t8][2] + bv), p2);
                p3 = fmaf(wv, tanh_pre(acc0[t8][3] + bv), p3);
                q0 = fmaf(wv, tanh_pre(acc1[t8][0] + bv), q0);
                q1 = fmaf(wv, tanh_pre(acc1[t8][1] + bv), q1);
                q2 = fmaf(wv, tanh_pre(acc1[t8][2] + bv), q2);
                q3 = fmaf(wv, tanh_pre(acc1[t8][3] + bv), q3);
            }
        }
    }

    // reduce over the 16 lanes (l15 bits) of each point-group
#pragma unroll
    for (int m = 1; m < 16; m <<= 1) {
        p0 += __shfl_xor(p0, m); p1 += __shfl_xor(p1, m);
        p2 += __shfl_xor(p2, m); p3 += __shfl_xor(p3, m);
        q0 += __shfl_xor(q0, m); q1 += __shfl_xor(q1, m);
        q2 += __shfl_xor(q2, m); q3 += __shfl_xor(q3, m);
    }
    if (l15 < 4) {
        float bo = b_out[bin];
        float v0 = ((l15 == 0) ? p0 : (l15 == 1) ? p1 : (l15 == 2) ? p2 : p3) + bo;
        float v1 = ((l15 == 0) ? q0 : (l15 == 1) ? q1 : (l15 == 2) ? q2 : q3) + bo;
        int pl0 = w * 32 + 4 * g + l15;
        int pl1 = pl0 + 16;
        int pid0 = lTid[pl0], pid1 = lTid[pl1];
        if (pid0 >= 0) atomicAdd(out + pid0, lWgt[pl0] * v0);  // <=2 addends: deterministic
        if (pid1 >= 0) atomicAdd(out + pid1, lWgt[pl1] * v1);
    }
}

extern "C" void kernel_launch(void* const* d_in, const int* in_sizes, int n_in,
                              void* d_out, int out_size, void* d_ws, size_t ws_size,
                              hipStream_t stream) {
    const float* x       = (const float*)d_in[0];
    const float* W_in    = (const float*)d_in[1];
    const float* b_in    = (const float*)d_in[2];
    const float* W_hid   = (const float*)d_in[3];
    const float* b_hid   = (const float*)d_in[4];
    const float* W_out   = (const float*)d_in[5];
    const float* b_out   = (const float*)d_in[6];
    const float* centers = (const float*)d_in[7];
    const float* scales  = (const float*)d_in[8];
    float* out = (float*)d_out;

    char* ws = (char*)d_ws;
    int* counts  = (int*)(ws);
    int* cursors = (int*)(ws + 128);
    int* offsets = (int*)(ws + 256);
    int* tasks   = (int*)(ws + TASKS_OFF);
    uint4* WfU4  = (uint4*)(ws + WF_OFF);

    hipMemsetAsync(d_out, 0, (size_t)out_size * sizeof(float), stream);
    hipMemsetAsync(ws, 0, 256, stream);

    k_prepw<<<dim3(768), dim3(256), 0, stream>>>(W_hid, WfU4);
    k_count<<<dim3(NPTS / 256), dim3(256), 0, stream>>>(x, counts, NPTS);
    k_scan<<<1, 32, 0, stream>>>(counts, offsets, cursors);
    k_scatter<<<dim3(NPTS / 256), dim3(256), 0, stream>>>(x, cursors, tasks, NPTS);
    k_mlp<<<dim3(TPB, NS), dim3(TMLP), 0, stream>>>(x, W_in, b_in, b_hid, W_out, b_out,
                                                    centers, scales, counts, offsets, tasks,
                                                    WfU4, out);
}

// Round 6
// 135.011 us; speedup vs baseline: 6.6331x; 1.0918x over previous
//
#include <hip/hip_runtime.h>

#define NS 32
#define WID 128
#define NHID 3
#define NPTS 262144
#define PTILE 256     // points per block (32 per wave)
#define TMLP 512      // 8 waves
#define TPB 68        // tiles per bin: capacity 17408 tasks/bin (proven R1-R4)

#define TASKS_OFF 512
#define WF_OFF (TASKS_OFF + 2 * NPTS * 4)
#define TANH_C 2.8853900817779268f   // 2*log2(e)

typedef _Float16 f16x2 __attribute__((ext_vector_type(2)));
typedef _Float16 f16x4 __attribute__((ext_vector_type(4)));
typedef _Float16 f16x8 __attribute__((ext_vector_type(8)));
typedef __fp16 fp16x2 __attribute__((ext_vector_type(2)));
typedef float f32x4 __attribute__((ext_vector_type(4)));

union U4H8 { uint4 u; f16x8 h; };
union PK2 { fp16x2 p; f16x2 h; };

__device__ __forceinline__ f16x2 pk2(float a, float b) {
    PK2 u; u.p = __builtin_amdgcn_cvt_pkrtz(a, b); return u.h;
}

__device__ __forceinline__ float tanh_fast(float v) {
    float a = v * TANH_C;
    float e; asm("v_exp_f32 %0, %1" : "=v"(e) : "v"(a));
    float d = e + 1.0f;
    float r; asm("v_rcp_f32 %0, %1" : "=v"(r) : "v"(d));
    return fmaf(-2.0f, r, 1.0f);
}

// input already pre-scaled by TANH_C (folded into Wf/bias)
__device__ __forceinline__ float tanh_pre(float a) {
    float e; asm("v_exp_f32 %0, %1" : "=v"(e) : "v"(a));
    float d = e + 1.0f;
    float r; asm("v_rcp_f32 %0, %1" : "=v"(r) : "v"(d));
    return fmaf(-2.0f, r, 1.0f);
}

__device__ __forceinline__ float coswin(float u) {
    if (fabsf(u) >= 1.0f) return 0.0f;
    float rev = u * 0.25f;
    float c; asm("v_cos_f32 %0, %1" : "=v"(c) : "v"(rev));
    return c * c;
}

// ---------------- bucketing (proven R0-R4) ----------------

__global__ void k_count(const float* __restrict__ x, int* __restrict__ counts, int n) {
    __shared__ int loc[NS];
    int t = threadIdx.x;
    if (t < NS) loc[t] = 0;
    __syncthreads();
    int i = blockIdx.x * blockDim.x + t;
    if (i < n) {
        float tt = x[i] * 32.0f;
        int j = (int)floorf(tt); j = min(max(j, 0), 31);
        atomicAdd(&loc[j], 1);
        float u = tt - (float)j - 0.5f;
        int nb = (u > 0.0f) ? j + 1 : j - 1;
        if (u != 0.0f && nb >= 0 && nb < NS) atomicAdd(&loc[nb], 1);
    }
    __syncthreads();
    if (t < NS) atomicAdd(&counts[t], loc[t]);
}

__global__ void k_scan(const int* __restrict__ counts, int* __restrict__ offsets,
                       int* __restrict__ cursors) {
    if (threadIdx.x == 0) {
        int acc = 0;
        for (int s = 0; s < NS; ++s) { offsets[s] = acc; cursors[s] = acc; acc += counts[s]; }
    }
}

__global__ void k_scatter(const float* __restrict__ x, int* __restrict__ cursors,
                          int* __restrict__ tasks, int n) {
    __shared__ int loc[NS];
    __shared__ int base[NS];
    int t = threadIdx.x;
    if (t < NS) loc[t] = 0;
    __syncthreads();
    int i = blockIdx.x * blockDim.x + t;
    int j = -1, nb = -1, sj = 0, snb = 0;
    if (i < n) {
        float tt = x[i] * 32.0f;
        j = min(max((int)floorf(tt), 0), 31);
        sj = atomicAdd(&loc[j], 1);
        float u = tt - (float)j - 0.5f;
        int nb2 = (u > 0.0f) ? j + 1 : j - 1;
        if (u != 0.0f && nb2 >= 0 && nb2 < NS) { nb = nb2; snb = atomicAdd(&loc[nb], 1); }
    }
    __syncthreads();
    if (t < NS) base[t] = atomicAdd(&cursors[t], loc[t]);
    __syncthreads();
    if (i < n) {
        tasks[base[j] + sj] = i;
        if (nb >= 0) tasks[base[nb] + snb] = i;
    }
}

// ---------------- W fragment pre-pack (fp16, MFMA B order, pre-scaled) ----------
// Wf[v][t8][s][lane]: e=0..7 -> k = 32s + 4*(lane>>4) + (e&3) + 16*(e>>2),
//                     o = 16*t8 + (lane&15); value = TANH_C * W_hid[v][o][k]

__global__ void k_prepw(const float* __restrict__ Wh, uint4* __restrict__ WfU4) {
    int tid = blockIdx.x * blockDim.x + threadIdx.x;
    if (tid >= 32 * 3 * 8 * 4 * 64) return;
    int lane = tid & 63;
    int s    = (tid >> 6) & 3;
    int t8   = (tid >> 8) & 7;
    int v    = tid >> 11;            // bin*3 + l, 0..95
    int o    = 16 * t8 + (lane & 15);
    const float* src = Wh + ((size_t)v * 128 + o) * 128;
    unsigned short b[8];
#pragma unroll
    for (int e = 0; e < 8; ++e) {
        int k = 32 * s + 4 * (lane >> 4) + (e & 3) + 16 * (e >> 2);
        _Float16 hv = (_Float16)(src[k] * TANH_C);
        b[e] = *(unsigned short*)&hv;
    }
    uint4 outv;
    outv.x = (unsigned)b[0] | ((unsigned)b[1] << 16);
    outv.y = (unsigned)b[2] | ((unsigned)b[3] << 16);
    outv.z = (unsigned)b[4] | ((unsigned)b[5] << 16);
    outv.w = (unsigned)b[6] | ((unsigned)b[7] << 16);
    WfU4[((size_t)(v * 8 + t8) * 4 + s) * 64 + lane] = outv;
}

// ---------------- main fused MLP: fp16 MFMA, 32 pts/wave, t8-pipelined ----------

__global__ __launch_bounds__(TMLP, 4) void k_mlp(
    const float* __restrict__ x, const float* __restrict__ W_in, const float* __restrict__ b_in,
    const float* __restrict__ b_hid, const float* __restrict__ W_out, const float* __restrict__ b_out,
    const float* __restrict__ centers, const float* __restrict__ scales,
    const int* __restrict__ counts, const int* __restrict__ offsets, const int* __restrict__ tasks,
    const uint4* __restrict__ WfU4, float* __restrict__ out) {

    const int bin = blockIdx.y;
    const int tile = blockIdx.x;
    const int cnt = counts[bin];
    if (tile * PTILE >= cnt) return;
    const int start = offsets[bin];

    // per-wave H^T: 2 point-sets x [k=0..127][p=0..15] fp16 = 8KB/wave
    __shared__ __align__(256) _Float16 HT[8][4096];
    __shared__ float lU[PTILE], lWgt[PTILE];
    __shared__ int lTid[PTILE];

    const int t = threadIdx.x;
    const int lane = t & 63;
    const int l15 = t & 15;
    const int g = (t >> 4) & 3;       // lane covers points 4g..4g+3 of each set
    const int w = t >> 6;             // wave id: points w*32 .. w*32+31

    if (t < PTILE) {
        int idx = tile * PTILE + t;
        if (idx < cnt) {
            int pid = tasks[start + idx];
            lTid[t] = pid;
            float xx = x[pid];
            float u = (xx - centers[bin]) * (1.0f / scales[bin]);
            lU[t] = u;
            float rs = coswin(u);
            int other = bin + (u > 0.0f ? 1 : -1);
            float ro = 0.0f;
            if (other >= 0 && other < NS)
                ro = coswin((xx - centers[other]) * (1.0f / scales[other]));
            lWgt[t] = rs / (rs + ro + 1e-8f);
        } else { lTid[t] = -1; lU[t] = 0.0f; lWgt[t] = 0.0f; }
    }
    __syncthreads();

    // ---- input layer: both point-sets (fp32 compute, fp16 store) ----
    {
        float4 ua = *(const float4*)&lU[w * 32 + 4 * g];
        float4 ub = *(const float4*)&lU[w * 32 + 16 + 4 * g];
        const float* Win = W_in + bin * WID;
        const float* Bi  = b_in + bin * WID;
#pragma unroll
        for (int t8 = 0; t8 < 8; ++t8) {
            int o = 16 * t8 + l15;
            float wv = Win[o], bv = Bi[o];
            f16x2 h00 = pk2(tanh_fast(fmaf(ua.x, wv, bv)), tanh_fast(fmaf(ua.y, wv, bv)));
            f16x2 h01 = pk2(tanh_fast(fmaf(ua.z, wv, bv)), tanh_fast(fmaf(ua.w, wv, bv)));
            f16x2 h10 = pk2(tanh_fast(fmaf(ub.x, wv, bv)), tanh_fast(fmaf(ub.y, wv, bv)));
            f16x2 h11 = pk2(tanh_fast(fmaf(ub.z, wv, bv)), tanh_fast(fmaf(ub.w, wv, bv)));
            *(f16x4*)&HT[w][o * 16 + 4 * g] = __builtin_shufflevector(h00, h01, 0, 1, 2, 3);
            *(f16x4*)&HT[w][2048 + o * 16 + 4 * g] = __builtin_shufflevector(h10, h11, 0, 1, 2, 3);
        }
    }
    // HT is wave-private; per-wave LDS ops are in-order -> no barrier needed.

    const unsigned htaddr = (unsigned)(size_t)&HT[w][0] + lane * 8;
    const uint4* wfbase = WfU4 + (size_t)(bin * NHID) * 32 * 64 + lane;
    float p0 = 0.f, p1 = 0.f, p2 = 0.f, p3 = 0.f;
    float q0 = 0.f, q1 = 0.f, q2 = 0.f, q3 = 0.f;

#pragma unroll
    for (int lyr = 0; lyr < NHID; ++lyr) {
        // ---- all A-fragments for this layer: 16 tr-reads, one wait ----
        f16x4 r0, r1, r2, r3, r4, r5, r6, r7, r8, r9, r10, r11, r12, r13, r14, r15;
        asm volatile(
            "ds_read_b64_tr_b16 %0, %16 offset:0\n\t"
            "ds_read_b64_tr_b16 %1, %16 offset:512\n\t"
            "ds_read_b64_tr_b16 %2, %16 offset:1024\n\t"
            "ds_read_b64_tr_b16 %3, %16 offset:1536\n\t"
            "ds_read_b64_tr_b16 %4, %16 offset:2048\n\t"
            "ds_read_b64_tr_b16 %5, %16 offset:2560\n\t"
            "ds_read_b64_tr_b16 %6, %16 offset:3072\n\t"
            "ds_read_b64_tr_b16 %7, %16 offset:3584\n\t"
            "ds_read_b64_tr_b16 %8, %16 offset:4096\n\t"
            "ds_read_b64_tr_b16 %9, %16 offset:4608\n\t"
            "ds_read_b64_tr_b16 %10, %16 offset:5120\n\t"
            "ds_read_b64_tr_b16 %11, %16 offset:5632\n\t"
            "ds_read_b64_tr_b16 %12, %16 offset:6144\n\t"
            "ds_read_b64_tr_b16 %13, %16 offset:6656\n\t"
            "ds_read_b64_tr_b16 %14, %16 offset:7168\n\t"
            "ds_read_b64_tr_b16 %15, %16 offset:7680\n\t"
            "s_waitcnt lgkmcnt(0)"
            : "=v"(r0), "=v"(r1), "=v"(r2), "=v"(r3), "=v"(r4), "=v"(r5), "=v"(r6), "=v"(r7),
              "=v"(r8), "=v"(r9), "=v"(r10), "=v"(r11), "=v"(r12), "=v"(r13), "=v"(r14), "=v"(r15)
            : "v"(htaddr) : "memory");
        f16x8 A0[4], A1[4];
        A0[0] = __builtin_shufflevector(r0, r1, 0, 1, 2, 3, 4, 5, 6, 7);
        A0[1] = __builtin_shufflevector(r2, r3, 0, 1, 2, 3, 4, 5, 6, 7);
        A0[2] = __builtin_shufflevector(r4, r5, 0, 1, 2, 3, 4, 5, 6, 7);
        A0[3] = __builtin_shufflevector(r6, r7, 0, 1, 2, 3, 4, 5, 6, 7);
        A1[0] = __builtin_shufflevector(r8, r9, 0, 1, 2, 3, 4, 5, 6, 7);
        A1[1] = __builtin_shufflevector(r10, r11, 0, 1, 2, 3, 4, 5, 6, 7);
        A1[2] = __builtin_shufflevector(r12, r13, 0, 1, 2, 3, 4, 5, 6, 7);
        A1[3] = __builtin_shufflevector(r14, r15, 0, 1, 2, 3, 4, 5, 6, 7);

        // per-lane bias (and Wo for last layer) preload
        const float* bh = b_hid + (size_t)(bin * NHID + lyr) * WID;
        float bhv[8];
#pragma unroll
        for (int t8 = 0; t8 < 8; ++t8) bhv[t8] = bh[16 * t8 + l15] * TANH_C;

        const uint4* wfL = wfbase + (size_t)lyr * 32 * 64;

        // ---- t8-pipelined MFMA + epilogue: double-buffered B fragments ----
        uint4 cur[4], nxt[4];
#pragma unroll
        for (int s = 0; s < 4; ++s) cur[s] = wfL[s * 64];

#pragma unroll
        for (int t8 = 0; t8 < 8; ++t8) {
            if (t8 < 7) {
#pragma unroll
                for (int s = 0; s < 4; ++s) nxt[s] = wfL[((t8 + 1) * 4 + s) * 64];
            }
            f32x4 acc0 = (f32x4){0.f, 0.f, 0.f, 0.f};
            f32x4 acc1 = (f32x4){0.f, 0.f, 0.f, 0.f};
            __builtin_amdgcn_s_setprio(1);
#pragma unroll
            for (int s = 0; s < 4; ++s) {
                U4H8 bw; bw.u = cur[s];
                acc0 = __builtin_amdgcn_mfma_f32_16x16x32_f16(A0[s], bw.h, acc0, 0, 0, 0);
                acc1 = __builtin_amdgcn_mfma_f32_16x16x32_f16(A1[s], bw.h, acc1, 0, 0, 0);
            }
            __builtin_amdgcn_s_setprio(0);

            if (lyr < NHID - 1) {
                int o = 16 * t8 + l15;
                float bv = bhv[t8];
                f16x2 h00 = pk2(tanh_pre(acc0[0] + bv), tanh_pre(acc0[1] + bv));
                f16x2 h01 = pk2(tanh_pre(acc0[2] + bv), tanh_pre(acc0[3] + bv));
                f16x2 h10 = pk2(tanh_pre(acc1[0] + bv), tanh_pre(acc1[1] + bv));
                f16x2 h11 = pk2(tanh_pre(acc1[2] + bv), tanh_pre(acc1[3] + bv));
                *(f16x4*)&HT[w][o * 16 + 4 * g] = __builtin_shufflevector(h00, h01, 0, 1, 2, 3);
                *(f16x4*)&HT[w][2048 + o * 16 + 4 * g] = __builtin_shufflevector(h10, h11, 0, 1, 2, 3);
            } else {
                float bv = bhv[t8];
                float wv = W_out[bin * WID + 16 * t8 + l15];
                p0 = fmaf(wv, tanh_pre(acc0[0] + bv), p0);
                p1 = fmaf(wv, tanh_pre(acc0[1] + bv), p1);
                p2 = fmaf(wv, tanh_pre(acc0[2] + bv), p2);
                p3 = fmaf(wv, tanh_pre(acc0[3] + bv), p3);
                q0 = fmaf(wv, tanh_pre(acc1[0] + bv), q0);
                q1 = fmaf(wv, tanh_pre(acc1[1] + bv), q1);
                q2 = fmaf(wv, tanh_pre(acc1[2] + bv), q2);
                q3 = fmaf(wv, tanh_pre(acc1[3] + bv), q3);
            }
#pragma unroll
            for (int s = 0; s < 4; ++s) cur[s] = nxt[s];
        }
    }

    // reduce over the 16 lanes (l15 bits) of each point-group
#pragma unroll
    for (int m = 1; m < 16; m <<= 1) {
        p0 += __shfl_xor(p0, m); p1 += __shfl_xor(p1, m);
        p2 += __shfl_xor(p2, m); p3 += __shfl_xor(p3, m);
        q0 += __shfl_xor(q0, m); q1 += __shfl_xor(q1, m);
        q2 += __shfl_xor(q2, m); q3 += __shfl_xor(q3, m);
    }
    if (l15 < 4) {
        float bo = b_out[bin];
        float v0 = ((l15 == 0) ? p0 : (l15 == 1) ? p1 : (l15 == 2) ? p2 : p3) + bo;
        float v1 = ((l15 == 0) ? q0 : (l15 == 1) ? q1 : (l15 == 2) ? q2 : q3) + bo;
        int pl0 = w * 32 + 4 * g + l15;
        int pl1 = pl0 + 16;
        int pid0 = lTid[pl0], pid1 = lTid[pl1];
        if (pid0 >= 0) atomicAdd(out + pid0, lWgt[pl0] * v0);  // <=2 addends: deterministic
        if (pid1 >= 0) atomicAdd(out + pid1, lWgt[pl1] * v1);
    }
}

extern "C" void kernel_launch(void* const* d_in, const int* in_sizes, int n_in,
                              void* d_out, int out_size, void* d_ws, size_t ws_size,
                              hipStream_t stream) {
    const float* x       = (const float*)d_in[0];
    const float* W_in    = (const float*)d_in[1];
    const float* b_in    = (const float*)d_in[2];
    const float* W_hid   = (const float*)d_in[3];
    const float* b_hid   = (const float*)d_in[4];
    const float* W_out   = (const float*)d_in[5];
    const float* b_out   = (const float*)d_in[6];
    const float* centers = (const float*)d_in[7];
    const float* scales  = (const float*)d_in[8];
    float* out = (float*)d_out;

    char* ws = (char*)d_ws;
    int* counts  = (int*)(ws);
    int* cursors = (int*)(ws + 128);
    int* offsets = (int*)(ws + 256);
    int* tasks   = (int*)(ws + TASKS_OFF);
    uint4* WfU4  = (uint4*)(ws + WF_OFF);

    (void)hipMemsetAsync(d_out, 0, (size_t)out_size * sizeof(float), stream);
    (void)hipMemsetAsync(ws, 0, 256, stream);

    k_prepw<<<dim3(768), dim3(256), 0, stream>>>(W_hid, WfU4);
    k_count<<<dim3(NPTS / 256), dim3(256), 0, stream>>>(x, counts, NPTS);
    k_scan<<<1, 32, 0, stream>>>(counts, offsets, cursors);
    k_scatter<<<dim3(NPTS / 256), dim3(256), 0, stream>>>(x, cursors, tasks, NPTS);
    k_mlp<<<dim3(TPB, NS), dim3(TMLP), 0, stream>>>(x, W_in, b_in, b_hid, W_out, b_out,
                                                    centers, scales, counts, offsets, tasks,
                                                    WfU4, out);
}

// Round 7
// 116.993 us; speedup vs baseline: 7.6546x; 1.1540x over previous
//
#include <hip/hip_runtime.h>

#define NS 32
#define WID 128
#define NHID 3
#define NPTS 262144
#define PTILE 256     // points per block (32 per wave)
#define TMLP 512      // 8 waves
#define CAP 17408     // per-bin task capacity (proven R1-R6)
#define TPB (CAP / PTILE)

#define TASKS_OFF 512
#define WF_OFF (TASKS_OFF + NS * CAP * 4)
#define TANH_C 2.8853900817779268f   // 2*log2(e)

typedef _Float16 f16x2 __attribute__((ext_vector_type(2)));
typedef _Float16 f16x4 __attribute__((ext_vector_type(4)));
typedef _Float16 f16x8 __attribute__((ext_vector_type(8)));
typedef __fp16 fp16x2 __attribute__((ext_vector_type(2)));
typedef float f32x4 __attribute__((ext_vector_type(4)));

union U4H8 { uint4 u; f16x8 h; };
union PK2 { fp16x2 p; f16x2 h; };

__device__ __forceinline__ f16x2 pk2(float a, float b) {
    PK2 u; u.p = __builtin_amdgcn_cvt_pkrtz(a, b); return u.h;
}

__device__ __forceinline__ float tanh_fast(float v) {
    float a = v * TANH_C;
    float e; asm("v_exp_f32 %0, %1" : "=v"(e) : "v"(a));
    float d = e + 1.0f;
    float r; asm("v_rcp_f32 %0, %1" : "=v"(r) : "v"(d));
    return fmaf(-2.0f, r, 1.0f);
}

// input already pre-scaled by TANH_C (folded into Wf/bias)
__device__ __forceinline__ float tanh_pre(float a) {
    float e; asm("v_exp_f32 %0, %1" : "=v"(e) : "v"(a));
    float d = e + 1.0f;
    float r; asm("v_rcp_f32 %0, %1" : "=v"(r) : "v"(d));
    return fmaf(-2.0f, r, 1.0f);
}

__device__ __forceinline__ float coswin(float u) {
    if (fabsf(u) >= 1.0f) return 0.0f;
    float rev = u * 0.25f;
    float c; asm("v_cos_f32 %0, %1" : "=v"(c) : "v"(rev));
    return c * c;
}

// ---------- fused bucketing: capacity-slotted scatter + out-zeroing ----------
// tasks[bin*CAP + slot]; slot order within a bin is schedule-dependent but the
// per-point result is order-independent (independent MFMA rows; 2-addend
// commutative atomicAdd) -> deterministic output.

__global__ void k_scatter2(const float* __restrict__ x, int* __restrict__ cursors,
                           int* __restrict__ tasks, float* __restrict__ out, int n) {
    __shared__ int loc[NS];
    __shared__ int base[NS];
    int t = threadIdx.x;
    if (t < NS) loc[t] = 0;
    __syncthreads();
    int i = blockIdx.x * blockDim.x + t;
    int j = -1, nb = -1, sj = 0, snb = 0;
    if (i < n) {
        out[i] = 0.0f;
        float tt = x[i] * 32.0f;
        j = min(max((int)floorf(tt), 0), 31);
        sj = atomicAdd(&loc[j], 1);
        float u = tt - (float)j - 0.5f;
        int nb2 = (u > 0.0f) ? j + 1 : j - 1;
        if (u != 0.0f && nb2 >= 0 && nb2 < NS) { nb = nb2; snb = atomicAdd(&loc[nb], 1); }
    }
    __syncthreads();
    if (t < NS) base[t] = atomicAdd(&cursors[t], loc[t]);
    __syncthreads();
    if (i < n) {
        tasks[j * CAP + base[j] + sj] = i;
        if (nb >= 0) tasks[nb * CAP + base[nb] + snb] = i;
    }
}

// ---------------- W fragment pre-pack (fp16, MFMA B order, pre-scaled) ----------
// Wf[v][t8][s][lane]: e=0..7 -> k = 32s + 4*(lane>>4) + (e&3) + 16*(e>>2),
//                     o = 16*t8 + (lane&15); value = TANH_C * W_hid[v][o][k]

__global__ void k_prepw(const float* __restrict__ Wh, uint4* __restrict__ WfU4) {
    int tid = blockIdx.x * blockDim.x + threadIdx.x;
    if (tid >= 32 * 3 * 8 * 4 * 64) return;
    int lane = tid & 63;
    int s    = (tid >> 6) & 3;
    int t8   = (tid >> 8) & 7;
    int v    = tid >> 11;            // bin*3 + l, 0..95
    int o    = 16 * t8 + (lane & 15);
    const float* src = Wh + ((size_t)v * 128 + o) * 128;
    unsigned short b[8];
#pragma unroll
    for (int e = 0; e < 8; ++e) {
        int k = 32 * s + 4 * (lane >> 4) + (e & 3) + 16 * (e >> 2);
        _Float16 hv = (_Float16)(src[k] * TANH_C);
        b[e] = *(unsigned short*)&hv;
    }
    uint4 outv;
    outv.x = (unsigned)b[0] | ((unsigned)b[1] << 16);
    outv.y = (unsigned)b[2] | ((unsigned)b[3] << 16);
    outv.z = (unsigned)b[4] | ((unsigned)b[5] << 16);
    outv.w = (unsigned)b[6] | ((unsigned)b[7] << 16);
    WfU4[((size_t)(v * 8 + t8) * 4 + s) * 64 + lane] = outv;
}

// ---------------- main fused MLP: fp16 MFMA, cross-layer pipelined B ----------

__global__ __launch_bounds__(TMLP, 4) void k_mlp(
    const float* __restrict__ x, const float* __restrict__ W_in, const float* __restrict__ b_in,
    const float* __restrict__ b_hid, const float* __restrict__ W_out, const float* __restrict__ b_out,
    const float* __restrict__ centers, const float* __restrict__ scales,
    const int* __restrict__ cursors, const int* __restrict__ tasks,
    const uint4* __restrict__ WfU4, float* __restrict__ out) {

    const int bin = blockIdx.y;
    const int tile = blockIdx.x;
    const int cnt = cursors[bin];
    if (tile * PTILE >= cnt) return;
    const int start = bin * CAP;

    // per-wave H^T: 2 point-sets x [k=0..127][p=0..15] fp16 = 8KB/wave
    __shared__ __align__(256) _Float16 HT[8][4096];
    __shared__ float lU[PTILE], lWgt[PTILE];
    __shared__ int lTid[PTILE];

    const int t = threadIdx.x;
    const int lane = t & 63;
    const int l15 = t & 15;
    const int g = (t >> 4) & 3;       // lane covers points 4g..4g+3 of each set
    const int w = t >> 6;             // wave id: points w*32 .. w*32+31

    if (t < PTILE) {
        int idx = tile * PTILE + t;
        if (idx < cnt) {
            int pid = tasks[start + idx];
            lTid[t] = pid;
            float xx = x[pid];
            float u = (xx - centers[bin]) * (1.0f / scales[bin]);
            lU[t] = u;
            float rs = coswin(u);
            int other = bin + (u > 0.0f ? 1 : -1);
            float ro = 0.0f;
            if (other >= 0 && other < NS)
                ro = coswin((xx - centers[other]) * (1.0f / scales[other]));
            lWgt[t] = rs / (rs + ro + 1e-8f);
        } else { lTid[t] = -1; lU[t] = 0.0f; lWgt[t] = 0.0f; }
    }
    __syncthreads();

    const uint4* wfbase = WfU4 + (size_t)(bin * NHID) * 32 * 64 + lane;

    // prologue of the B-pipeline: layer 0, t8=0 (covered by input-layer compute)
    uint4 bufA[4], bufB[4];
#pragma unroll
    for (int s = 0; s < 4; ++s) bufA[s] = wfbase[s * 64];

    // ---- input layer: both point-sets (fp32 compute, fp16 store) ----
    {
        float4 ua = *(const float4*)&lU[w * 32 + 4 * g];
        float4 ub = *(const float4*)&lU[w * 32 + 16 + 4 * g];
        const float* Win = W_in + bin * WID;
        const float* Bi  = b_in + bin * WID;
#pragma unroll
        for (int t8 = 0; t8 < 8; ++t8) {
            int o = 16 * t8 + l15;
            float wv = Win[o], bv = Bi[o];
            f16x2 h00 = pk2(tanh_fast(fmaf(ua.x, wv, bv)), tanh_fast(fmaf(ua.y, wv, bv)));
            f16x2 h01 = pk2(tanh_fast(fmaf(ua.z, wv, bv)), tanh_fast(fmaf(ua.w, wv, bv)));
            f16x2 h10 = pk2(tanh_fast(fmaf(ub.x, wv, bv)), tanh_fast(fmaf(ub.y, wv, bv)));
            f16x2 h11 = pk2(tanh_fast(fmaf(ub.z, wv, bv)), tanh_fast(fmaf(ub.w, wv, bv)));
            *(f16x4*)&HT[w][o * 16 + 4 * g] = __builtin_shufflevector(h00, h01, 0, 1, 2, 3);
            *(f16x4*)&HT[w][2048 + o * 16 + 4 * g] = __builtin_shufflevector(h10, h11, 0, 1, 2, 3);
        }
    }
    // HT is wave-private; per-wave LDS ops are in-order -> no barrier needed.

    const unsigned htaddr = (unsigned)(size_t)&HT[w][0] + lane * 8;
    float p0 = 0.f, p1 = 0.f, p2 = 0.f, p3 = 0.f;
    float q0 = 0.f, q1 = 0.f, q2 = 0.f, q3 = 0.f;

#pragma unroll
    for (int lyr = 0; lyr < NHID; ++lyr) {
        // bias (and Wo) preload first: L2 latency hides under the tr bundle
        const float* bh = b_hid + (size_t)(bin * NHID + lyr) * WID;
        float bhv[8], wov[8];
#pragma unroll
        for (int t8 = 0; t8 < 8; ++t8) bhv[t8] = bh[16 * t8 + l15] * TANH_C;
        if (lyr == NHID - 1) {
#pragma unroll
            for (int t8 = 0; t8 < 8; ++t8) wov[t8] = W_out[bin * WID + 16 * t8 + l15];
        }

        // ---- all A-fragments for this layer: 16 tr-reads, one wait ----
        f16x4 r0, r1, r2, r3, r4, r5, r6, r7, r8, r9, r10, r11, r12, r13, r14, r15;
        asm volatile(
            "ds_read_b64_tr_b16 %0, %16 offset:0\n\t"
            "ds_read_b64_tr_b16 %1, %16 offset:512\n\t"
            "ds_read_b64_tr_b16 %2, %16 offset:1024\n\t"
            "ds_read_b64_tr_b16 %3, %16 offset:1536\n\t"
            "ds_read_b64_tr_b16 %4, %16 offset:2048\n\t"
            "ds_read_b64_tr_b16 %5, %16 offset:2560\n\t"
            "ds_read_b64_tr_b16 %6, %16 offset:3072\n\t"
            "ds_read_b64_tr_b16 %7, %16 offset:3584\n\t"
            "ds_read_b64_tr_b16 %8, %16 offset:4096\n\t"
            "ds_read_b64_tr_b16 %9, %16 offset:4608\n\t"
            "ds_read_b64_tr_b16 %10, %16 offset:5120\n\t"
            "ds_read_b64_tr_b16 %11, %16 offset:5632\n\t"
            "ds_read_b64_tr_b16 %12, %16 offset:6144\n\t"
            "ds_read_b64_tr_b16 %13, %16 offset:6656\n\t"
            "ds_read_b64_tr_b16 %14, %16 offset:7168\n\t"
            "ds_read_b64_tr_b16 %15, %16 offset:7680\n\t"
            "s_waitcnt lgkmcnt(0)"
            : "=v"(r0), "=v"(r1), "=v"(r2), "=v"(r3), "=v"(r4), "=v"(r5), "=v"(r6), "=v"(r7),
              "=v"(r8), "=v"(r9), "=v"(r10), "=v"(r11), "=v"(r12), "=v"(r13), "=v"(r14), "=v"(r15)
            : "v"(htaddr) : "memory");
        f16x8 A0[4], A1[4];
        A0[0] = __builtin_shufflevector(r0, r1, 0, 1, 2, 3, 4, 5, 6, 7);
        A0[1] = __builtin_shufflevector(r2, r3, 0, 1, 2, 3, 4, 5, 6, 7);
        A0[2] = __builtin_shufflevector(r4, r5, 0, 1, 2, 3, 4, 5, 6, 7);
        A0[3] = __builtin_shufflevector(r6, r7, 0, 1, 2, 3, 4, 5, 6, 7);
        A1[0] = __builtin_shufflevector(r8, r9, 0, 1, 2, 3, 4, 5, 6, 7);
        A1[1] = __builtin_shufflevector(r10, r11, 0, 1, 2, 3, 4, 5, 6, 7);
        A1[2] = __builtin_shufflevector(r12, r13, 0, 1, 2, 3, 4, 5, 6, 7);
        A1[3] = __builtin_shufflevector(r14, r15, 0, 1, 2, 3, 4, 5, 6, 7);

        const uint4* wfL = wfbase + (size_t)lyr * 32 * 64;
        const uint4* wfN = wfbase + (size_t)(lyr + 1) * 32 * 64;  // next layer (if any)

        // ---- even/odd t8 pipeline: bufA/bufB alternate, loads 1 step ahead ----
#pragma unroll
        for (int tp = 0; tp < 4; ++tp) {
            const int t8a = 2 * tp, t8b = 2 * tp + 1;
            // prefetch B for t8b
#pragma unroll
            for (int s = 0; s < 4; ++s) bufB[s] = wfL[(t8b * 4 + s) * 64];

            f32x4 acc0 = (f32x4){0.f, 0.f, 0.f, 0.f};
            f32x4 acc1 = (f32x4){0.f, 0.f, 0.f, 0.f};
            __builtin_amdgcn_s_setprio(1);
#pragma unroll
            for (int s = 0; s < 4; ++s) {
                U4H8 bw; bw.u = bufA[s];
                acc0 = __builtin_amdgcn_mfma_f32_16x16x32_f16(A0[s], bw.h, acc0, 0, 0, 0);
                acc1 = __builtin_amdgcn_mfma_f32_16x16x32_f16(A1[s], bw.h, acc1, 0, 0, 0);
            }
            __builtin_amdgcn_s_setprio(0);

            if (lyr < NHID - 1) {
                int o = 16 * t8a + l15;
                float bv = bhv[t8a];
                f16x2 h00 = pk2(tanh_pre(acc0[0] + bv), tanh_pre(acc0[1] + bv));
                f16x2 h01 = pk2(tanh_pre(acc0[2] + bv), tanh_pre(acc0[3] + bv));
                f16x2 h10 = pk2(tanh_pre(acc1[0] + bv), tanh_pre(acc1[1] + bv));
                f16x2 h11 = pk2(tanh_pre(acc1[2] + bv), tanh_pre(acc1[3] + bv));
                *(f16x4*)&HT[w][o * 16 + 4 * g] = __builtin_shufflevector(h00, h01, 0, 1, 2, 3);
                *(f16x4*)&HT[w][2048 + o * 16 + 4 * g] = __builtin_shufflevector(h10, h11, 0, 1, 2, 3);
            } else {
                float bv = bhv[t8a], wv = wov[t8a];
                p0 = fmaf(wv, tanh_pre(acc0[0] + bv), p0);
                p1 = fmaf(wv, tanh_pre(acc0[1] + bv), p1);
                p2 = fmaf(wv, tanh_pre(acc0[2] + bv), p2);
                p3 = fmaf(wv, tanh_pre(acc0[3] + bv), p3);
                q0 = fmaf(wv, tanh_pre(acc1[0] + bv), q0);
                q1 = fmaf(wv, tanh_pre(acc1[1] + bv), q1);
                q2 = fmaf(wv, tanh_pre(acc1[2] + bv), q2);
                q3 = fmaf(wv, tanh_pre(acc1[3] + bv), q3);
            }

            // prefetch B for t8a+2 (or next layer's t8=0 across the boundary)
            if (t8b < 7) {
#pragma unroll
                for (int s = 0; s < 4; ++s) bufA[s] = wfL[((t8b + 1) * 4 + s) * 64];
            } else if (lyr < NHID - 1) {
#pragma unroll
                for (int s = 0; s < 4; ++s) bufA[s] = wfN[s * 64];
            }

            f32x4 bcc0 = (f32x4){0.f, 0.f, 0.f, 0.f};
            f32x4 bcc1 = (f32x4){0.f, 0.f, 0.f, 0.f};
            __builtin_amdgcn_s_setprio(1);
#pragma unroll
            for (int s = 0; s < 4; ++s) {
                U4H8 bw; bw.u = bufB[s];
                bcc0 = __builtin_amdgcn_mfma_f32_16x16x32_f16(A0[s], bw.h, bcc0, 0, 0, 0);
                bcc1 = __builtin_amdgcn_mfma_f32_16x16x32_f16(A1[s], bw.h, bcc1, 0, 0, 0);
            }
            __builtin_amdgcn_s_setprio(0);

            if (lyr < NHID - 1) {
                int o = 16 * t8b + l15;
                float bv = bhv[t8b];
                f16x2 h00 = pk2(tanh_pre(bcc0[0] + bv), tanh_pre(bcc0[1] + bv));
                f16x2 h01 = pk2(tanh_pre(bcc0[2] + bv), tanh_pre(bcc0[3] + bv));
                f16x2 h10 = pk2(tanh_pre(bcc1[0] + bv), tanh_pre(bcc1[1] + bv));
                f16x2 h11 = pk2(tanh_pre(bcc1[2] + bv), tanh_pre(bcc1[3] + bv));
                *(f16x4*)&HT[w][o * 16 + 4 * g] = __builtin_shufflevector(h00, h01, 0, 1, 2, 3);
                *(f16x4*)&HT[w][2048 + o * 16 + 4 * g] = __builtin_shufflevector(h10, h11, 0, 1, 2, 3);
            } else {
                float bv = bhv[t8b], wv = wov[t8b];
                p0 = fmaf(wv, tanh_pre(bcc0[0] + bv), p0);
                p1 = fmaf(wv, tanh_pre(bcc0[1] + bv), p1);
                p2 = fmaf(wv, tanh_pre(bcc0[2] + bv), p2);
                p3 = fmaf(wv, tanh_pre(bcc0[3] + bv), p3);
                q0 = fmaf(wv, tanh_pre(bcc1[0] + bv), q0);
                q1 = fmaf(wv, tanh_pre(bcc1[1] + bv), q1);
                q2 = fmaf(wv, tanh_pre(bcc1[2] + bv), q2);
                q3 = fmaf(wv, tanh_pre(bcc1[3] + bv), q3);
            }
        }
    }

    // reduce over the 16 lanes (l15 bits) of each point-group
#pragma unroll
    for (int m = 1; m < 16; m <<= 1) {
        p0 += __shfl_xor(p0, m); p1 += __shfl_xor(p1, m);
        p2 += __shfl_xor(p2, m); p3 += __shfl_xor(p3, m);
        q0 += __shfl_xor(q0, m); q1 += __shfl_xor(q1, m);
        q2 += __shfl_xor(q2, m); q3 += __shfl_xor(q3, m);
    }
    if (l15 < 4) {
        float bo = b_out[bin];
        float v0 = ((l15 == 0) ? p0 : (l15 == 1) ? p1 : (l15 == 2) ? p2 : p3) + bo;
        float v1 = ((l15 == 0) ? q0 : (l15 == 1) ? q1 : (l15 == 2) ? q2 : q3) + bo;
        int pl0 = w * 32 + 4 * g + l15;
        int pl1 = pl0 + 16;
        int pid0 = lTid[pl0], pid1 = lTid[pl1];
        if (pid0 >= 0) atomicAdd(out + pid0, lWgt[pl0] * v0);  // <=2 addends: deterministic
        if (pid1 >= 0) atomicAdd(out + pid1, lWgt[pl1] * v1);
    }
}

extern "C" void kernel_launch(void* const* d_in, const int* in_sizes, int n_in,
                              void* d_out, int out_size, void* d_ws, size_t ws_size,
                              hipStream_t stream) {
    const float* x       = (const float*)d_in[0];
    const float* W_in    = (const float*)d_in[1];
    const float* b_in    = (const float*)d_in[2];
    const float* W_hid   = (const float*)d_in[3];
    const float* b_hid   = (const float*)d_in[4];
    const float* W_out   = (const float*)d_in[5];
    const float* b_out   = (const float*)d_in[6];
    const float* centers = (const float*)d_in[7];
    const float* scales  = (const float*)d_in[8];
    float* out = (float*)d_out;

    char* ws = (char*)d_ws;
    int* cursors = (int*)(ws);
    int* tasks   = (int*)(ws + TASKS_OFF);
    uint4* WfU4  = (uint4*)(ws + WF_OFF);

    (void)hipMemsetAsync(ws, 0, 256, stream);

    k_prepw<<<dim3(768), dim3(256), 0, stream>>>(W_hid, WfU4);
    k_scatter2<<<dim3(NPTS / 256), dim3(256), 0, stream>>>(x, cursors, tasks, out, NPTS);
    k_mlp<<<dim3(TPB, NS), dim3(TMLP), 0, stream>>>(x, W_in, b_in, b_hid, W_out, b_out,
                                                    centers, scales, cursors, tasks,
                                                    WfU4, out);
}

// Round 11
// 113.339 us; speedup vs baseline: 7.9014x; 1.0322x over previous
//
#include <hip/hip_runtime.h>

#define NS 32
#define WID 128
#define NHID 3
#define NPTS 262144
#define PTILE 256     // points per block (32 per wave)
#define TMLP 512      // 8 waves
#define CAP 17408     // per-bin task capacity (proven R1-R7)
#define TPB (CAP / PTILE)

#define TASKS_OFF 512
#define WF_OFF (TASKS_OFF + NS * CAP * 4)
#define TANH_C 2.8853900817779268f   // 2*log2(e)

typedef _Float16 f16x2 __attribute__((ext_vector_type(2)));
typedef _Float16 f16x4 __attribute__((ext_vector_type(4)));
typedef _Float16 f16x8 __attribute__((ext_vector_type(8)));
typedef __fp16 fp16x2 __attribute__((ext_vector_type(2)));
typedef float f32x4 __attribute__((ext_vector_type(4)));

union U4H8 { uint4 u; f16x8 h; };
union PK2 { fp16x2 p; f16x2 h; };
union H4U2 { f16x4 h; uint2 u; };

__device__ __forceinline__ f16x2 pk2(float a, float b) {
    PK2 u; u.p = __builtin_amdgcn_cvt_pkrtz(a, b); return u.h;
}

__device__ __forceinline__ float tanh_fast(float v) {
    float a = v * TANH_C;
    float e; asm("v_exp_f32 %0, %1" : "=v"(e) : "v"(a));
    float d = e + 1.0f;
    float r; asm("v_rcp_f32 %0, %1" : "=v"(r) : "v"(d));
    return fmaf(-2.0f, r, 1.0f);
}

// input already pre-scaled by TANH_C (folded into Wf/bias)
__device__ __forceinline__ float tanh_pre(float a) {
    float e; asm("v_exp_f32 %0, %1" : "=v"(e) : "v"(a));
    float d = e + 1.0f;
    float r; asm("v_rcp_f32 %0, %1" : "=v"(r) : "v"(d));
    return fmaf(-2.0f, r, 1.0f);
}

__device__ __forceinline__ float coswin(float u) {
    if (fabsf(u) >= 1.0f) return 0.0f;
    float rev = u * 0.25f;
    float c; asm("v_cos_f32 %0, %1" : "=v"(c) : "v"(rev));
    return c * c;
}

// ---------- fused prep: blocks 0..95 pack Wf (LDS-staged, coalesced); ----------
// ---------- blocks 96.. do capacity-slotted scatter + out-zeroing      ----------
// tasks[bin*CAP + slot]; slot order is schedule-dependent but the per-point
// result is order-independent (independent rows; <=2-addend commutative atomicAdd).
// Wf[v][t8][s][lane]: e=0..7 -> k = 32s + 4*(lane>>4) + (e&3) + 16*(e>>2),
//                     o = 16*t8 + (lane&15); value = TANH_C * W_hid[v][o][k]
// (element-for-element identical to R7's passing k_prepw layout)

__global__ __launch_bounds__(256) void k_prep(
    const float* __restrict__ Wh, uint4* __restrict__ WfU4,
    const float* __restrict__ x, int* __restrict__ cursors,
    int* __restrict__ tasks, float* __restrict__ out, int n) {
    __shared__ _Float16 sW[128 * 132];   // 33 KB, +4 fp16 row pad
    __shared__ int loc[NS];
    __shared__ int base[NS];
    const int b = blockIdx.x;
    const int t = threadIdx.x;
    if (b < 96) {
        const float* src = Wh + (size_t)b * 16384;
#pragma unroll
        for (int it = 0; it < 16; ++it) {
            int idx = it * 1024 + t * 4;
            int o = idx >> 7, c = idx & 127;
            float4 v = *(const float4*)(src + idx);
            f16x4 hv;
            hv[0] = (_Float16)(v.x * TANH_C);
            hv[1] = (_Float16)(v.y * TANH_C);
            hv[2] = (_Float16)(v.z * TANH_C);
            hv[3] = (_Float16)(v.w * TANH_C);
            *(f16x4*)&sW[o * 132 + c] = hv;
        }
        __syncthreads();
#pragma unroll
        for (int it = 0; it < 8; ++it) {
            int f = it * 256 + t;
            int lane = f & 63, s = (f >> 6) & 3, t8 = f >> 8;
            int o = 16 * t8 + (lane & 15), h = lane >> 4;
            H4U2 lo, hi;
            lo.h = *(f16x4*)&sW[o * 132 + 32 * s + 4 * h];
            hi.h = *(f16x4*)&sW[o * 132 + 32 * s + 4 * h + 16];
            uint4 outv = {lo.u.x, lo.u.y, hi.u.x, hi.u.y};
            WfU4[(size_t)b * 2048 + f] = outv;
        }
    } else {
        if (t < NS) loc[t] = 0;
        __syncthreads();
        int i = (b - 96) * 256 + t;
        int j = -1, nb = -1, sj = 0, snb = 0;
        if (i < n) {
            out[i] = 0.0f;
            float tt = x[i] * 32.0f;
            j = min(max((int)floorf(tt), 0), 31);
            sj = atomicAdd(&loc[j], 1);
            float u = tt - (float)j - 0.5f;
            int nb2 = (u > 0.0f) ? j + 1 : j - 1;
            if (u != 0.0f && nb2 >= 0 && nb2 < NS) { nb = nb2; snb = atomicAdd(&loc[nb], 1); }
        }
        __syncthreads();
        if (t < NS) base[t] = atomicAdd(&cursors[t], loc[t]);
        __syncthreads();
        if (i < n) {
            tasks[j * CAP + base[j] + sj] = i;
            if (nb >= 0) tasks[nb * CAP + base[nb] + snb] = i;
        }
    }
}

// ---------------- main fused MLP: R7-proven kernel (compiler-managed B prefetch,
// ---------------- fp16 MFMA, 32 pts/wave, even/odd t8 pipeline) -----------------

__global__ __launch_bounds__(TMLP, 4) void k_mlp(
    const float* __restrict__ x, const float* __restrict__ W_in, const float* __restrict__ b_in,
    const float* __restrict__ b_hid, const float* __restrict__ W_out, const float* __restrict__ b_out,
    const float* __restrict__ centers, const float* __restrict__ scales,
    const int* __restrict__ cursors, const int* __restrict__ tasks,
    const uint4* __restrict__ WfU4, float* __restrict__ out) {

    const int bin = blockIdx.y;
    const int tile = blockIdx.x;
    const int cnt = cursors[bin];
    if (tile * PTILE >= cnt) return;
    const int start = bin * CAP;

    // per-wave H^T: 2 point-sets x [k=0..127][p=0..15] fp16 = 8KB/wave
    __shared__ __align__(256) _Float16 HT[8][4096];
    __shared__ float lU[PTILE], lWgt[PTILE];
    __shared__ int lTid[PTILE];

    const int t = threadIdx.x;
    const int lane = t & 63;
    const int l15 = t & 15;
    const int g = (t >> 4) & 3;       // lane covers points 4g..4g+3 of each set
    const int w = t >> 6;             // wave id: points w*32 .. w*32+31

    if (t < PTILE) {
        int idx = tile * PTILE + t;
        if (idx < cnt) {
            int pid = tasks[start + idx];
            lTid[t] = pid;
            float xx = x[pid];
            float u = (xx - centers[bin]) * (1.0f / scales[bin]);
            lU[t] = u;
            float rs = coswin(u);
            int other = bin + (u > 0.0f ? 1 : -1);
            float ro = 0.0f;
            if (other >= 0 && other < NS)
                ro = coswin((xx - centers[other]) * (1.0f / scales[other]));
            lWgt[t] = rs / (rs + ro + 1e-8f);
        } else { lTid[t] = -1; lU[t] = 0.0f; lWgt[t] = 0.0f; }
    }
    __syncthreads();

    const uint4* wfbase = WfU4 + (size_t)(bin * NHID) * 32 * 64 + lane;

    // prologue of the B-pipeline: layer 0, t8=0 (covered by input-layer compute)
    uint4 bufA[4], bufB[4];
#pragma unroll
    for (int s = 0; s < 4; ++s) bufA[s] = wfbase[s * 64];

    // ---- input layer: both point-sets (fp32 compute, fp16 store) ----
    {
        float4 ua = *(const float4*)&lU[w * 32 + 4 * g];
        float4 ub = *(const float4*)&lU[w * 32 + 16 + 4 * g];
        const float* Win = W_in + bin * WID;
        const float* Bi  = b_in + bin * WID;
#pragma unroll
        for (int t8 = 0; t8 < 8; ++t8) {
            int o = 16 * t8 + l15;
            float wv = Win[o], bv = Bi[o];
            f16x2 h00 = pk2(tanh_fast(fmaf(ua.x, wv, bv)), tanh_fast(fmaf(ua.y, wv, bv)));
            f16x2 h01 = pk2(tanh_fast(fmaf(ua.z, wv, bv)), tanh_fast(fmaf(ua.w, wv, bv)));
            f16x2 h10 = pk2(tanh_fast(fmaf(ub.x, wv, bv)), tanh_fast(fmaf(ub.y, wv, bv)));
            f16x2 h11 = pk2(tanh_fast(fmaf(ub.z, wv, bv)), tanh_fast(fmaf(ub.w, wv, bv)));
            *(f16x4*)&HT[w][o * 16 + 4 * g] = __builtin_shufflevector(h00, h01, 0, 1, 2, 3);
            *(f16x4*)&HT[w][2048 + o * 16 + 4 * g] = __builtin_shufflevector(h10, h11, 0, 1, 2, 3);
        }
    }
    // HT is wave-private; per-wave LDS ops are in-order -> no barrier needed.

    const unsigned htaddr = (unsigned)(size_t)&HT[w][0] + lane * 8;
    float p0 = 0.f, p1 = 0.f, p2 = 0.f, p3 = 0.f;
    float q0 = 0.f, q1 = 0.f, q2 = 0.f, q3 = 0.f;

#pragma unroll
    for (int lyr = 0; lyr < NHID; ++lyr) {
        // ---- all A-fragments for this layer: 16 tr-reads, one wait ----
        f16x4 r0, r1, r2, r3, r4, r5, r6, r7, r8, r9, r10, r11, r12, r13, r14, r15;
        asm volatile(
            "ds_read_b64_tr_b16 %0, %16 offset:0\n\t"
            "ds_read_b64_tr_b16 %1, %16 offset:512\n\t"
            "ds_read_b64_tr_b16 %2, %16 offset:1024\n\t"
            "ds_read_b64_tr_b16 %3, %16 offset:1536\n\t"
            "ds_read_b64_tr_b16 %4, %16 offset:2048\n\t"
            "ds_read_b64_tr_b16 %5, %16 offset:2560\n\t"
            "ds_read_b64_tr_b16 %6, %16 offset:3072\n\t"
            "ds_read_b64_tr_b16 %7, %16 offset:3584\n\t"
            "ds_read_b64_tr_b16 %8, %16 offset:4096\n\t"
            "ds_read_b64_tr_b16 %9, %16 offset:4608\n\t"
            "ds_read_b64_tr_b16 %10, %16 offset:5120\n\t"
            "ds_read_b64_tr_b16 %11, %16 offset:5632\n\t"
            "ds_read_b64_tr_b16 %12, %16 offset:6144\n\t"
            "ds_read_b64_tr_b16 %13, %16 offset:6656\n\t"
            "ds_read_b64_tr_b16 %14, %16 offset:7168\n\t"
            "ds_read_b64_tr_b16 %15, %16 offset:7680\n\t"
            "s_waitcnt lgkmcnt(0)"
            : "=v"(r0), "=v"(r1), "=v"(r2), "=v"(r3), "=v"(r4), "=v"(r5), "=v"(r6), "=v"(r7),
              "=v"(r8), "=v"(r9), "=v"(r10), "=v"(r11), "=v"(r12), "=v"(r13), "=v"(r14), "=v"(r15)
            : "v"(htaddr) : "memory");
        f16x8 A0[4], A1[4];
        A0[0] = __builtin_shufflevector(r0, r1, 0, 1, 2, 3, 4, 5, 6, 7);
        A0[1] = __builtin_shufflevector(r2, r3, 0, 1, 2, 3, 4, 5, 6, 7);
        A0[2] = __builtin_shufflevector(r4, r5, 0, 1, 2, 3, 4, 5, 6, 7);
        A0[3] = __builtin_shufflevector(r6, r7, 0, 1, 2, 3, 4, 5, 6, 7);
        A1[0] = __builtin_shufflevector(r8, r9, 0, 1, 2, 3, 4, 5, 6, 7);
        A1[1] = __builtin_shufflevector(r10, r11, 0, 1, 2, 3, 4, 5, 6, 7);
        A1[2] = __builtin_shufflevector(r12, r13, 0, 1, 2, 3, 4, 5, 6, 7);
        A1[3] = __builtin_shufflevector(r14, r15, 0, 1, 2, 3, 4, 5, 6, 7);

        // per-lane bias (and Wo for last layer) preload
        const float* bh = b_hid + (size_t)(bin * NHID + lyr) * WID;
        float bhv[8];
#pragma unroll
        for (int t8 = 0; t8 < 8; ++t8) bhv[t8] = bh[16 * t8 + l15] * TANH_C;

        const uint4* wfL = wfbase + (size_t)lyr * 32 * 64;
        const uint4* wfN = wfbase + (size_t)(lyr + 1) * 32 * 64;  // next layer (if any)

        // ---- even/odd t8 pipeline: bufA/bufB alternate, loads 1 step ahead ----
#pragma unroll
        for (int tp = 0; tp < 4; ++tp) {
            const int t8a = 2 * tp, t8b = 2 * tp + 1;
            // prefetch B for t8b
#pragma unroll
            for (int s = 0; s < 4; ++s) bufB[s] = wfL[(t8b * 4 + s) * 64];

            f32x4 acc0 = (f32x4){0.f, 0.f, 0.f, 0.f};
            f32x4 acc1 = (f32x4){0.f, 0.f, 0.f, 0.f};
            __builtin_amdgcn_s_setprio(1);
#pragma unroll
            for (int s = 0; s < 4; ++s) {
                U4H8 bw; bw.u = bufA[s];
                acc0 = __builtin_amdgcn_mfma_f32_16x16x32_f16(A0[s], bw.h, acc0, 0, 0, 0);
                acc1 = __builtin_amdgcn_mfma_f32_16x16x32_f16(A1[s], bw.h, acc1, 0, 0, 0);
            }
            __builtin_amdgcn_s_setprio(0);

            if (lyr < NHID - 1) {
                int o = 16 * t8a + l15;
                float bv = bhv[t8a];
                f16x2 h00 = pk2(tanh_pre(acc0[0] + bv), tanh_pre(acc0[1] + bv));
                f16x2 h01 = pk2(tanh_pre(acc0[2] + bv), tanh_pre(acc0[3] + bv));
                f16x2 h10 = pk2(tanh_pre(acc1[0] + bv), tanh_pre(acc1[1] + bv));
                f16x2 h11 = pk2(tanh_pre(acc1[2] + bv), tanh_pre(acc1[3] + bv));
                *(f16x4*)&HT[w][o * 16 + 4 * g] = __builtin_shufflevector(h00, h01, 0, 1, 2, 3);
                *(f16x4*)&HT[w][2048 + o * 16 + 4 * g] = __builtin_shufflevector(h10, h11, 0, 1, 2, 3);
            } else {
                float bv = bhv[t8a], wv = W_out[bin * WID + 16 * t8a + l15];
                p0 = fmaf(wv, tanh_pre(acc0[0] + bv), p0);
                p1 = fmaf(wv, tanh_pre(acc0[1] + bv), p1);
                p2 = fmaf(wv, tanh_pre(acc0[2] + bv), p2);
                p3 = fmaf(wv, tanh_pre(acc0[3] + bv), p3);
                q0 = fmaf(wv, tanh_pre(acc1[0] + bv), q0);
                q1 = fmaf(wv, tanh_pre(acc1[1] + bv), q1);
                q2 = fmaf(wv, tanh_pre(acc1[2] + bv), q2);
                q3 = fmaf(wv, tanh_pre(acc1[3] + bv), q3);
            }

            // prefetch B for t8a+2 (or next layer's t8=0 across the boundary)
            if (t8b < 7) {
#pragma unroll
                for (int s = 0; s < 4; ++s) bufA[s] = wfL[((t8b + 1) * 4 + s) * 64];
            } else if (lyr < NHID - 1) {
#pragma unroll
                for (int s = 0; s < 4; ++s) bufA[s] = wfN[s * 64];
            }

            f32x4 bcc0 = (f32x4){0.f, 0.f, 0.f, 0.f};
            f32x4 bcc1 = (f32x4){0.f, 0.f, 0.f, 0.f};
            __builtin_amdgcn_s_setprio(1);
#pragma unroll
            for (int s = 0; s < 4; ++s) {
                U4H8 bw; bw.u = bufB[s];
                bcc0 = __builtin_amdgcn_mfma_f32_16x16x32_f16(A0[s], bw.h, bcc0, 0, 0, 0);
                bcc1 = __builtin_amdgcn_mfma_f32_16x16x32_f16(A1[s], bw.h, bcc1, 0, 0, 0);
            }
            __builtin_amdgcn_s_setprio(0);

            if (lyr < NHID - 1) {
                int o = 16 * t8b + l15;
                float bv = bhv[t8b];
                f16x2 h00 = pk2(tanh_pre(bcc0[0] + bv), tanh_pre(bcc0[1] + bv));
                f16x2 h01 = pk2(tanh_pre(bcc0[2] + bv), tanh_pre(bcc0[3] + bv));
                f16x2 h10 = pk2(tanh_pre(bcc1[0] + bv), tanh_pre(bcc1[1] + bv));
                f16x2 h11 = pk2(tanh_pre(bcc1[2] + bv), tanh_pre(bcc1[3] + bv));
                *(f16x4*)&HT[w][o * 16 + 4 * g] = __builtin_shufflevector(h00, h01, 0, 1, 2, 3);
                *(f16x4*)&HT[w][2048 + o * 16 + 4 * g] = __builtin_shufflevector(h10, h11, 0, 1, 2, 3);
            } else {
                float bv = bhv[t8b], wv = W_out[bin * WID + 16 * t8b + l15];
                p0 = fmaf(wv, tanh_pre(bcc0[0] + bv), p0);
                p1 = fmaf(wv, tanh_pre(bcc0[1] + bv), p1);
                p2 = fmaf(wv, tanh_pre(bcc0[2] + bv), p2);
                p3 = fmaf(wv, tanh_pre(bcc0[3] + bv), p3);
                q0 = fmaf(wv, tanh_pre(bcc1[0] + bv), q0);
                q1 = fmaf(wv, tanh_pre(bcc1[1] + bv), q1);
                q2 = fmaf(wv, tanh_pre(bcc1[2] + bv), q2);
                q3 = fmaf(wv, tanh_pre(bcc1[3] + bv), q3);
            }
        }
    }

    // reduce over the 16 lanes (l15 bits) of each point-group
#pragma unroll
    for (int m = 1; m < 16; m <<= 1) {
        p0 += __shfl_xor(p0, m); p1 += __shfl_xor(p1, m);
        p2 += __shfl_xor(p2, m); p3 += __shfl_xor(p3, m);
        q0 += __shfl_xor(q0, m); q1 += __shfl_xor(q1, m);
        q2 += __shfl_xor(q2, m); q3 += __shfl_xor(q3, m);
    }
    if (l15 < 4) {
        float bo = b_out[bin];
        float v0 = ((l15 == 0) ? p0 : (l15 == 1) ? p1 : (l15 == 2) ? p2 : p3) + bo;
        float v1 = ((l15 == 0) ? q0 : (l15 == 1) ? q1 : (l15 == 2) ? q2 : q3) + bo;
        int pl0 = w * 32 + 4 * g + l15;
        int pl1 = pl0 + 16;
        int pid0 = lTid[pl0], pid1 = lTid[pl1];
        if (pid0 >= 0) atomicAdd(out + pid0, lWgt[pl0] * v0);  // <=2 addends: deterministic
        if (pid1 >= 0) atomicAdd(out + pid1, lWgt[pl1] * v1);
    }
}

extern "C" void kernel_launch(void* const* d_in, const int* in_sizes, int n_in,
                              void* d_out, int out_size, void* d_ws, size_t ws_size,
                              hipStream_t stream) {
    const float* x       = (const float*)d_in[0];
    const float* W_in    = (const float*)d_in[1];
    const float* b_in    = (const float*)d_in[2];
    const float* W_hid   = (const float*)d_in[3];
    const float* b_hid   = (const float*)d_in[4];
    const float* W_out   = (const float*)d_in[5];
    const float* b_out   = (const float*)d_in[6];
    const float* centers = (const float*)d_in[7];
    const float* scales  = (const float*)d_in[8];
    float* out = (float*)d_out;

    char* ws = (char*)d_ws;
    int* cursors = (int*)(ws);
    int* tasks   = (int*)(ws + TASKS_OFF);
    uint4* WfU4  = (uint4*)(ws + WF_OFF);

    (void)hipMemsetAsync(ws, 0, 256, stream);

    k_prep<<<dim3(96 + NPTS / 256), dim3(256), 0, stream>>>(W_hid, WfU4, x, cursors,
                                                            tasks, out, NPTS);
    k_mlp<<<dim3(TPB, NS), dim3(TMLP), 0, stream>>>(x, W_in, b_in, b_hid, W_out, b_out,
                                                    centers, scales, cursors, tasks,
                                                    WfU4, out);
}

// Round 15
// 112.475 us; speedup vs baseline: 7.9621x; 1.0077x over previous
//
#include <hip/hip_runtime.h>

#define NS 32
#define WID 128
#define NHID 3
#define NPTS 262144
#define PTILE 256     // points per block (32 per wave)
#define TMLP 512      // 8 waves
#define CAP 17408     // per-bin task capacity (proven R1-R11)
#define TPB (CAP / PTILE)

#define TASKS_OFF 512
#define WF_OFF (TASKS_OFF + NS * CAP * 4)
#define TANH_C 2.8853900817779268f   // 2*log2(e)

typedef _Float16 f16x2 __attribute__((ext_vector_type(2)));
typedef _Float16 f16x4 __attribute__((ext_vector_type(4)));
typedef _Float16 f16x8 __attribute__((ext_vector_type(8)));
typedef __fp16 fp16x2 __attribute__((ext_vector_type(2)));
typedef float f32x4 __attribute__((ext_vector_type(4)));

union U4H8 { uint4 u; f16x8 h; };
union PK2 { fp16x2 p; f16x2 h; };
union H4U2 { f16x4 h; uint2 u; };

__device__ __forceinline__ f16x2 pk2(float a, float b) {
    PK2 u; u.p = __builtin_amdgcn_cvt_pkrtz(a, b); return u.h;
}

__device__ __forceinline__ float tanh_fast(float v) {
    float a = v * TANH_C;
    float e; asm("v_exp_f32 %0, %1" : "=v"(e) : "v"(a));
    float d = e + 1.0f;
    float r; asm("v_rcp_f32 %0, %1" : "=v"(r) : "v"(d));
    return fmaf(-2.0f, r, 1.0f);
}

// input already pre-scaled by TANH_C (Wf and staged b_hid carry the factor)
__device__ __forceinline__ float tanh_pre(float a) {
    float e; asm("v_exp_f32 %0, %1" : "=v"(e) : "v"(a));
    float d = e + 1.0f;
    float r; asm("v_rcp_f32 %0, %1" : "=v"(r) : "v"(d));
    return fmaf(-2.0f, r, 1.0f);
}

__device__ __forceinline__ float coswin(float u) {
    if (fabsf(u) >= 1.0f) return 0.0f;
    float rev = u * 0.25f;
    float c; asm("v_cos_f32 %0, %1" : "=v"(c) : "v"(rev));
    return c * c;
}

// issue 4 pinned global_load_dwordx4 (one B-step = 4 s-fragments)
#define ISSUE4(B, A)                                                     \
    asm volatile(                                                        \
        "global_load_dwordx4 %0, %4, off\n\t"                            \
        "global_load_dwordx4 %1, %4, off offset:1024\n\t"                \
        "global_load_dwordx4 %2, %4, off offset:2048\n\t"                \
        "global_load_dwordx4 %3, %4, off offset:3072"                    \
        : "=&v"(B[0]), "=&v"(B[1]), "=&v"(B[2]), "=&v"(B[3]) : "v"(A))

// ---------- fused prep: blocks 0..95 pack Wf; blocks 96.. scatter + out-zero ----
// (verbatim from R11-passing)

__global__ __launch_bounds__(256) void k_prep(
    const float* __restrict__ Wh, uint4* __restrict__ WfU4,
    const float* __restrict__ x, int* __restrict__ cursors,
    int* __restrict__ tasks, float* __restrict__ out, int n) {
    __shared__ _Float16 sW[128 * 132];   // 33 KB, +4 fp16 row pad
    __shared__ int loc[NS];
    __shared__ int base[NS];
    const int b = blockIdx.x;
    const int t = threadIdx.x;
    if (b < 96) {
        const float* src = Wh + (size_t)b * 16384;
#pragma unroll
        for (int it = 0; it < 16; ++it) {
            int idx = it * 1024 + t * 4;
            int o = idx >> 7, c = idx & 127;
            float4 v = *(const float4*)(src + idx);
            f16x4 hv;
            hv[0] = (_Float16)(v.x * TANH_C);
            hv[1] = (_Float16)(v.y * TANH_C);
            hv[2] = (_Float16)(v.z * TANH_C);
            hv[3] = (_Float16)(v.w * TANH_C);
            *(f16x4*)&sW[o * 132 + c] = hv;
        }
        __syncthreads();
#pragma unroll
        for (int it = 0; it < 8; ++it) {
            int f = it * 256 + t;
            int lane = f & 63, s = (f >> 6) & 3, t8 = f >> 8;
            int o = 16 * t8 + (lane & 15), h = lane >> 4;
            H4U2 lo, hi;
            lo.h = *(f16x4*)&sW[o * 132 + 32 * s + 4 * h];
            hi.h = *(f16x4*)&sW[o * 132 + 32 * s + 4 * h + 16];
            uint4 outv = {lo.u.x, lo.u.y, hi.u.x, hi.u.y};
            WfU4[(size_t)b * 2048 + f] = outv;
        }
    } else {
        if (t < NS) loc[t] = 0;
        __syncthreads();
        int i = (b - 96) * 256 + t;
        int j = -1, nb = -1, sj = 0, snb = 0;
        if (i < n) {
            out[i] = 0.0f;
            float tt = x[i] * 32.0f;
            j = min(max((int)floorf(tt), 0), 31);
            sj = atomicAdd(&loc[j], 1);
            float u = tt - (float)j - 0.5f;
            int nb2 = (u > 0.0f) ? j + 1 : j - 1;
            if (u != 0.0f && nb2 >= 0 && nb2 < NS) { nb = nb2; snb = atomicAdd(&loc[nb], 1); }
        }
        __syncthreads();
        if (t < NS) base[t] = atomicAdd(&cursors[t], loc[t]);
        __syncthreads();
        if (i < n) {
            tasks[j * CAP + base[j] + sj] = i;
            if (nb >= 0) tasks[nb * CAP + base[nb] + snb] = i;
        }
    }
}

// ------- main fused MLP: 2-deep asm-pinned B pipeline, counted vmcnt, ZERO-seed
// ------- C + epilogue bias-add (the R3-R11 proven numerics; bias-seed is BANNED:
// ------- it correlates 6/6 with correctness failures). No early-out.
// Invariant: after __syncthreads, the ONLY VMEM ops until the final vmcnt(0)
// consume are the asm ISSUE4 loads (all params incl. b_out staged to sPar LDS
// pre-barrier; barrier's implicit vmcnt(0) drains the staging loads).

__global__ __launch_bounds__(TMLP, 4) void k_mlp(
    const float* __restrict__ x, const float* __restrict__ W_in, const float* __restrict__ b_in,
    const float* __restrict__ b_hid, const float* __restrict__ W_out, const float* __restrict__ b_out,
    const float* __restrict__ centers, const float* __restrict__ scales,
    const int* __restrict__ cursors, const int* __restrict__ tasks,
    const uint4* __restrict__ WfU4, float* __restrict__ out) {

    const int bin = blockIdx.y;
    const int tile = blockIdx.x;
    const int cnt = cursors[bin];
    if (tile * PTILE >= cnt) return;
    const int start = bin * CAP;

    // per-wave H^T: 2 point-sets x [k=0..127][p=0..15] fp16 = 8KB/wave
    __shared__ __align__(256) _Float16 HT[8][4096];
    __shared__ float lU[PTILE], lWgt[PTILE];
    __shared__ int lTid[PTILE];
    __shared__ float sPar[769];  // [0,128)Win [128,256)bin [256,640)bhid*TC [640,768)Wout [768]bout

    const int t = threadIdx.x;
    const int lane = t & 63;
    const int l15 = t & 15;
    const int g = (t >> 4) & 3;       // lane covers points 4g..4g+3 of each set
    const int w = t >> 6;             // wave id: points w*32 .. w*32+31

    if (t < PTILE) {
        int idx = tile * PTILE + t;
        if (idx < cnt) {
            int pid = tasks[start + idx];
            lTid[t] = pid;
            float xx = x[pid];
            float u = (xx - centers[bin]) * (1.0f / scales[bin]);
            lU[t] = u;
            float rs = coswin(u);
            int other = bin + (u > 0.0f ? 1 : -1);
            float ro = 0.0f;
            if (other >= 0 && other < NS)
                ro = coswin((xx - centers[other]) * (1.0f / scales[other]));
            lWgt[t] = rs / (rs + ro + 1e-8f);
        } else { lTid[t] = -1; lU[t] = 0.0f; lWgt[t] = 0.0f; }
    } else {
        int j = t - 256;   // stage ALL small params into LDS (drained by the barrier)
#pragma unroll
        for (int r = 0; r < 3; ++r) {
            int ii = r * 256 + j;
            if (ii < 128)        sPar[ii] = W_in[bin * WID + ii];
            else if (ii < 256)   sPar[ii] = b_in[bin * WID + ii - 128];
            else if (ii < 640)   sPar[ii] = b_hid[bin * 384 + ii - 256] * TANH_C;
            else if (ii < 768)   sPar[ii] = W_out[bin * WID + ii - 640];
        }
        if (j == 255) sPar[768] = b_out[bin];
    }
    __syncthreads();

    // ---- B-pipeline prologue: loads for steps 0,1 (covered by input-layer tanh) ----
    unsigned long long wfa = (unsigned long long)(WfU4 + (size_t)(bin * NHID) * 2048)
                           + (unsigned long long)(lane) * 16ull;
    uint4 B0[4], B1[4];
    ISSUE4(B0, wfa); wfa += 4096;
    ISSUE4(B1, wfa); wfa += 4096;

    // ---- input layer: both point-sets (fp32 compute, fp16 store), LDS params only ----
    {
        float4 ua = *(const float4*)&lU[w * 32 + 4 * g];
        float4 ub = *(const float4*)&lU[w * 32 + 16 + 4 * g];
#pragma unroll
        for (int t8 = 0; t8 < 8; ++t8) {
            int o = 16 * t8 + l15;
            float wv = sPar[o], bv = sPar[128 + o];
            f16x2 h00 = pk2(tanh_fast(fmaf(ua.x, wv, bv)), tanh_fast(fmaf(ua.y, wv, bv)));
            f16x2 h01 = pk2(tanh_fast(fmaf(ua.z, wv, bv)), tanh_fast(fmaf(ua.w, wv, bv)));
            f16x2 h10 = pk2(tanh_fast(fmaf(ub.x, wv, bv)), tanh_fast(fmaf(ub.y, wv, bv)));
            f16x2 h11 = pk2(tanh_fast(fmaf(ub.z, wv, bv)), tanh_fast(fmaf(ub.w, wv, bv)));
            *(f16x4*)&HT[w][o * 16 + 4 * g] = __builtin_shufflevector(h00, h01, 0, 1, 2, 3);
            *(f16x4*)&HT[w][2048 + o * 16 + 4 * g] = __builtin_shufflevector(h10, h11, 0, 1, 2, 3);
        }
    }
    // HT is wave-private; per-wave LDS ops are in-order -> no barrier needed.

    const unsigned htaddr = (unsigned)(size_t)&HT[w][0] + lane * 8;
    float p0 = 0.f, p1 = 0.f, p2 = 0.f, p3 = 0.f;
    float q0 = 0.f, q1 = 0.f, q2 = 0.f, q3 = 0.f;

#pragma unroll
    for (int lyr = 0; lyr < NHID; ++lyr) {
        // ---- all A-fragments for this layer: 16 tr-reads, one wait ----
        f16x4 r0, r1, r2, r3, r4, r5, r6, r7, r8, r9, r10, r11, r12, r13, r14, r15;
        asm volatile(
            "ds_read_b64_tr_b16 %0, %16 offset:0\n\t"
            "ds_read_b64_tr_b16 %1, %16 offset:512\n\t"
            "ds_read_b64_tr_b16 %2, %16 offset:1024\n\t"
            "ds_read_b64_tr_b16 %3, %16 offset:1536\n\t"
            "ds_read_b64_tr_b16 %4, %16 offset:2048\n\t"
            "ds_read_b64_tr_b16 %5, %16 offset:2560\n\t"
            "ds_read_b64_tr_b16 %6, %16 offset:3072\n\t"
            "ds_read_b64_tr_b16 %7, %16 offset:3584\n\t"
            "ds_read_b64_tr_b16 %8, %16 offset:4096\n\t"
            "ds_read_b64_tr_b16 %9, %16 offset:4608\n\t"
            "ds_read_b64_tr_b16 %10, %16 offset:5120\n\t"
            "ds_read_b64_tr_b16 %11, %16 offset:5632\n\t"
            "ds_read_b64_tr_b16 %12, %16 offset:6144\n\t"
            "ds_read_b64_tr_b16 %13, %16 offset:6656\n\t"
            "ds_read_b64_tr_b16 %14, %16 offset:7168\n\t"
            "ds_read_b64_tr_b16 %15, %16 offset:7680\n\t"
            "s_waitcnt lgkmcnt(0)"
            : "=v"(r0), "=v"(r1), "=v"(r2), "=v"(r3), "=v"(r4), "=v"(r5), "=v"(r6), "=v"(r7),
              "=v"(r8), "=v"(r9), "=v"(r10), "=v"(r11), "=v"(r12), "=v"(r13), "=v"(r14), "=v"(r15)
            : "v"(htaddr) : "memory");
        __builtin_amdgcn_sched_barrier(0);   // rule-18 fence
        f16x8 A0[4], A1[4];
        A0[0] = __builtin_shufflevector(r0, r1, 0, 1, 2, 3, 4, 5, 6, 7);
        A0[1] = __builtin_shufflevector(r2, r3, 0, 1, 2, 3, 4, 5, 6, 7);
        A0[2] = __builtin_shufflevector(r4, r5, 0, 1, 2, 3, 4, 5, 6, 7);
        A0[3] = __builtin_shufflevector(r6, r7, 0, 1, 2, 3, 4, 5, 6, 7);
        A1[0] = __builtin_shufflevector(r8, r9, 0, 1, 2, 3, 4, 5, 6, 7);
        A1[1] = __builtin_shufflevector(r10, r11, 0, 1, 2, 3, 4, 5, 6, 7);
        A1[2] = __builtin_shufflevector(r12, r13, 0, 1, 2, 3, 4, 5, 6, 7);
        A1[3] = __builtin_shufflevector(r14, r15, 0, 1, 2, 3, 4, 5, 6, 7);

#pragma unroll
        for (int t8 = 0; t8 < 8; ++t8) {
            const int i = lyr * 8 + t8;
            // top-of-step wait: drain this step's 4 loads (issued 2 steps ago)
            if (i < 23) asm volatile("s_waitcnt vmcnt(4)" ::: "memory");
            else        asm volatile("s_waitcnt vmcnt(0)" ::: "memory");
            __builtin_amdgcn_sched_barrier(0);

            f32x4 acc0 = (f32x4){0.f, 0.f, 0.f, 0.f};   // ZERO seed (proven); bias in epilogue
            f32x4 acc1 = (f32x4){0.f, 0.f, 0.f, 0.f};
            __builtin_amdgcn_s_setprio(1);
#pragma unroll
            for (int s = 0; s < 4; ++s) {
                U4H8 bw;
                bw.u = (i % 2 == 0) ? B0[s] : B1[s];
                acc0 = __builtin_amdgcn_mfma_f32_16x16x32_f16(A0[s], bw.h, acc0, 0, 0, 0);
                acc1 = __builtin_amdgcn_mfma_f32_16x16x32_f16(A1[s], bw.h, acc1, 0, 0, 0);
            }
            __builtin_amdgcn_s_setprio(0);
            __builtin_amdgcn_sched_barrier(0);   // keep MFMAs above the re-issue

            // re-issue the just-consumed buffer for step i+2 (cover: epilogue + 1 step)
            if (i < 22) {
                if (i % 2 == 0) { ISSUE4(B0, wfa); }
                else            { ISSUE4(B1, wfa); }
                wfa += 4096;
            }

            float bv = sPar[256 + lyr * 128 + 16 * t8 + l15];   // LDS, lgkm domain
            if (lyr < NHID - 1) {
                int o = 16 * t8 + l15;
                f16x2 h00 = pk2(tanh_pre(acc0[0] + bv), tanh_pre(acc0[1] + bv));
                f16x2 h01 = pk2(tanh_pre(acc0[2] + bv), tanh_pre(acc0[3] + bv));
                f16x2 h10 = pk2(tanh_pre(acc1[0] + bv), tanh_pre(acc1[1] + bv));
                f16x2 h11 = pk2(tanh_pre(acc1[2] + bv), tanh_pre(acc1[3] + bv));
                *(f16x4*)&HT[w][o * 16 + 4 * g] = __builtin_shufflevector(h00, h01, 0, 1, 2, 3);
                *(f16x4*)&HT[w][2048 + o * 16 + 4 * g] = __builtin_shufflevector(h10, h11, 0, 1, 2, 3);
            } else {
                float wv = sPar[640 + 16 * t8 + l15];
                p0 = fmaf(wv, tanh_pre(acc0[0] + bv), p0);
                p1 = fmaf(wv, tanh_pre(acc0[1] + bv), p1);
                p2 = fmaf(wv, tanh_pre(acc0[2] + bv), p2);
                p3 = fmaf(wv, tanh_pre(acc0[3] + bv), p3);
                q0 = fmaf(wv, tanh_pre(acc1[0] + bv), q0);
                q1 = fmaf(wv, tanh_pre(acc1[1] + bv), q1);
                q2 = fmaf(wv, tanh_pre(acc1[2] + bv), q2);
                q3 = fmaf(wv, tanh_pre(acc1[3] + bv), q3);
            }
        }
    }

    // reduce over the 16 lanes (l15 bits) of each point-group
#pragma unroll
    for (int m = 1; m < 16; m <<= 1) {
        p0 += __shfl_xor(p0, m); p1 += __shfl_xor(p1, m);
        p2 += __shfl_xor(p2, m); p3 += __shfl_xor(p3, m);
        q0 += __shfl_xor(q0, m); q1 += __shfl_xor(q1, m);
        q2 += __shfl_xor(q2, m); q3 += __shfl_xor(q3, m);
    }
    if (l15 < 4) {
        float bo = sPar[768];   // staged pre-barrier (no compiler VMEM in counted region)
        float v0 = ((l15 == 0) ? p0 : (l15 == 1) ? p1 : (l15 == 2) ? p2 : p3) + bo;
        float v1 = ((l15 == 0) ? q0 : (l15 == 1) ? q1 : (l15 == 2) ? q2 : q3) + bo;
        int pl0 = w * 32 + 4 * g + l15;
        int pl1 = pl0 + 16;
        int pid0 = lTid[pl0], pid1 = lTid[pl1];
        if (pid0 >= 0) atomicAdd(out + pid0, lWgt[pl0] * v0);  // <=2 addends: deterministic
        if (pid1 >= 0) atomicAdd(out + pid1, lWgt[pl1] * v1);
    }
}

extern "C" void kernel_launch(void* const* d_in, const int* in_sizes, int n_in,
                              void* d_out, int out_size, void* d_ws, size_t ws_size,
                              hipStream_t stream) {
    const float* x       = (const float*)d_in[0];
    const float* W_in    = (const float*)d_in[1];
    const float* b_in    = (const float*)d_in[2];
    const float* W_hid   = (const float*)d_in[3];
    const float* b_hid   = (const float*)d_in[4];
    const float* W_out   = (const float*)d_in[5];
    const float* b_out   = (const float*)d_in[6];
    const float* centers = (const float*)d_in[7];
    const float* scales  = (const float*)d_in[8];
    float* out = (float*)d_out;

    char* ws = (char*)d_ws;
    int* cursors = (int*)(ws);
    int* tasks   = (int*)(ws + TASKS_OFF);
    uint4* WfU4  = (uint4*)(ws + WF_OFF);

    (void)hipMemsetAsync(ws, 0, 256, stream);

    k_prep<<<dim3(96 + NPTS / 256), dim3(256), 0, stream>>>(W_hid, WfU4, x, cursors,
                                                            tasks, out, NPTS);
    k_mlp<<<dim3(TPB, NS), dim3(TMLP), 0, stream>>>(x, W_in, b_in, b_hid, W_out, b_out,
                                                    centers, scales, cursors, tasks,
                                                    WfU4, out);
}

// Round 16
// 110.735 us; speedup vs baseline: 8.0872x; 1.0157x over previous
//
#include <hip/hip_runtime.h>

#define NS 32
#define WID 128
#define NHID 3
#define NPTS 262144
#define PTILE 256     // points per block (32 per wave)
#define TMLP 512      // 8 waves
#define CAP 17408     // per-bin task capacity (proven R1-R15)
#define TPB (CAP / PTILE)

#define TASKS_OFF 512
#define WF_OFF (TASKS_OFF + NS * CAP * 4)
#define TANH_C 2.8853900817779268f   // 2*log2(e)

typedef _Float16 f16x2 __attribute__((ext_vector_type(2)));
typedef _Float16 f16x4 __attribute__((ext_vector_type(4)));
typedef _Float16 f16x8 __attribute__((ext_vector_type(8)));
typedef __fp16 fp16x2 __attribute__((ext_vector_type(2)));
typedef float f32x4 __attribute__((ext_vector_type(4)));

union U4H8 { uint4 u; f16x8 h; };
union PK2 { fp16x2 p; f16x2 h; };
union H4U2 { f16x4 h; uint2 u; };

__device__ __forceinline__ f16x2 pk2(float a, float b) {
    PK2 u; u.p = __builtin_amdgcn_cvt_pkrtz(a, b); return u.h;
}

// input already pre-scaled by TANH_C (Wf and ALL staged params carry the factor)
__device__ __forceinline__ float tanh_pre(float a) {
    float e; asm("v_exp_f32 %0, %1" : "=v"(e) : "v"(a));
    float d = e + 1.0f;
    float r; asm("v_rcp_f32 %0, %1" : "=v"(r) : "v"(d));
    return fmaf(-2.0f, r, 1.0f);
}

__device__ __forceinline__ float coswin(float u) {
    if (fabsf(u) >= 1.0f) return 0.0f;
    float rev = u * 0.25f;
    float c; asm("v_cos_f32 %0, %1" : "=v"(c) : "v"(rev));
    return c * c;
}

// issue 4 pinned global_load_dwordx4 (one B-step = 4 s-fragments)
#define ISSUE4(B, A)                                                     \
    asm volatile(                                                        \
        "global_load_dwordx4 %0, %4, off\n\t"                            \
        "global_load_dwordx4 %1, %4, off offset:1024\n\t"                \
        "global_load_dwordx4 %2, %4, off offset:2048\n\t"                \
        "global_load_dwordx4 %3, %4, off offset:3072"                    \
        : "=&v"(B[0]), "=&v"(B[1]), "=&v"(B[2]), "=&v"(B[3]) : "v"(A))

// ---------- fused prep: blocks 0..95 pack Wf; blocks 96.. scatter + out-zero ----
// (verbatim from R11/R15-passing)

__global__ __launch_bounds__(256) void k_prep(
    const float* __restrict__ Wh, uint4* __restrict__ WfU4,
    const float* __restrict__ x, int* __restrict__ cursors,
    int* __restrict__ tasks, float* __restrict__ out, int n) {
    __shared__ _Float16 sW[128 * 132];   // 33 KB, +4 fp16 row pad
    __shared__ int loc[NS];
    __shared__ int base[NS];
    const int b = blockIdx.x;
    const int t = threadIdx.x;
    if (b < 96) {
        const float* src = Wh + (size_t)b * 16384;
#pragma unroll
        for (int it = 0; it < 16; ++it) {
            int idx = it * 1024 + t * 4;
            int o = idx >> 7, c = idx & 127;
            float4 v = *(const float4*)(src + idx);
            f16x4 hv;
            hv[0] = (_Float16)(v.x * TANH_C);
            hv[1] = (_Float16)(v.y * TANH_C);
            hv[2] = (_Float16)(v.z * TANH_C);
            hv[3] = (_Float16)(v.w * TANH_C);
            *(f16x4*)&sW[o * 132 + c] = hv;
        }
        __syncthreads();
#pragma unroll
        for (int it = 0; it < 8; ++it) {
            int f = it * 256 + t;
            int lane = f & 63, s = (f >> 6) & 3, t8 = f >> 8;
            int o = 16 * t8 + (lane & 15), h = lane >> 4;
            H4U2 lo, hi;
            lo.h = *(f16x4*)&sW[o * 132 + 32 * s + 4 * h];
            hi.h = *(f16x4*)&sW[o * 132 + 32 * s + 4 * h + 16];
            uint4 outv = {lo.u.x, lo.u.y, hi.u.x, hi.u.y};
            WfU4[(size_t)b * 2048 + f] = outv;
        }
    } else {
        if (t < NS) loc[t] = 0;
        __syncthreads();
        int i = (b - 96) * 256 + t;
        int j = -1, nb = -1, sj = 0, snb = 0;
        if (i < n) {
            out[i] = 0.0f;
            float tt = x[i] * 32.0f;
            j = min(max((int)floorf(tt), 0), 31);
            sj = atomicAdd(&loc[j], 1);
            float u = tt - (float)j - 0.5f;
            int nb2 = (u > 0.0f) ? j + 1 : j - 1;
            if (u != 0.0f && nb2 >= 0 && nb2 < NS) { nb = nb2; snb = atomicAdd(&loc[nb], 1); }
        }
        __syncthreads();
        if (t < NS) base[t] = atomicAdd(&cursors[t], loc[t]);
        __syncthreads();
        if (i < n) {
            tasks[j * CAP + base[j] + sj] = i;
            if (nb >= 0) tasks[nb * CAP + base[nb] + snb] = i;
        }
    }
}

// ------- main fused MLP: R15-passing structure; ALL params pre-scaled at LDS
// ------- staging (bias-seed remains BANNED: 6/6 failure correlation) -----------

__global__ __launch_bounds__(TMLP, 4) void k_mlp(
    const float* __restrict__ x, const float* __restrict__ W_in, const float* __restrict__ b_in,
    const float* __restrict__ b_hid, const float* __restrict__ W_out, const float* __restrict__ b_out,
    const float* __restrict__ centers, const float* __restrict__ scales,
    const int* __restrict__ cursors, const int* __restrict__ tasks,
    const uint4* __restrict__ WfU4, float* __restrict__ out) {

    const int bin = blockIdx.y;
    const int tile = blockIdx.x;
    const int cnt = cursors[bin];
    if (tile * PTILE >= cnt) return;
    const int start = bin * CAP;

    // per-wave H^T: 2 point-sets x [k=0..127][p=0..15] fp16 = 8KB/wave
    __shared__ __align__(256) _Float16 HT[8][4096];
    __shared__ float lU[PTILE], lWgt[PTILE];
    __shared__ int lTid[PTILE];
    __shared__ float sPar[769];  // [0,128)Win*TC [128,256)bin*TC [256,640)bhid*TC [640,768)Wout [768]bout

    const int t = threadIdx.x;
    const int lane = t & 63;
    const int l15 = t & 15;
    const int g = (t >> 4) & 3;       // lane covers points 4g..4g+3 of each set
    const int w = t >> 6;             // wave id: points w*32 .. w*32+31

    if (t < PTILE) {
        int idx = tile * PTILE + t;
        if (idx < cnt) {
            int pid = tasks[start + idx];
            lTid[t] = pid;
            float xx = x[pid];
            float u = (xx - centers[bin]) * (1.0f / scales[bin]);
            lU[t] = u;
            float rs = coswin(u);
            int other = bin + (u > 0.0f ? 1 : -1);
            float ro = 0.0f;
            if (other >= 0 && other < NS)
                ro = coswin((xx - centers[other]) * (1.0f / scales[other]));
            lWgt[t] = rs / (rs + ro + 1e-8f);
        } else { lTid[t] = -1; lU[t] = 0.0f; lWgt[t] = 0.0f; }
    } else {
        int j = t - 256;   // stage ALL small params into LDS, pre-scaled (barrier drains)
#pragma unroll
        for (int r = 0; r < 3; ++r) {
            int ii = r * 256 + j;
            if (ii < 128)        sPar[ii] = W_in[bin * WID + ii] * TANH_C;
            else if (ii < 256)   sPar[ii] = b_in[bin * WID + ii - 128] * TANH_C;
            else if (ii < 640)   sPar[ii] = b_hid[bin * 384 + ii - 256] * TANH_C;
            else if (ii < 768)   sPar[ii] = W_out[bin * WID + ii - 640];
        }
        if (j == 255) sPar[768] = b_out[bin];
    }
    __syncthreads();

    // ---- B-pipeline prologue: loads for steps 0,1 (covered by input-layer tanh) ----
    unsigned long long wfa = (unsigned long long)(WfU4 + (size_t)(bin * NHID) * 2048)
                           + (unsigned long long)(lane) * 16ull;
    uint4 B0[4], B1[4];
    ISSUE4(B0, wfa); wfa += 4096;
    ISSUE4(B1, wfa); wfa += 4096;

    // ---- input layer: both point-sets; params pre-scaled at staging ----
    {
        float4 ua = *(const float4*)&lU[w * 32 + 4 * g];
        float4 ub = *(const float4*)&lU[w * 32 + 16 + 4 * g];
#pragma unroll
        for (int t8 = 0; t8 < 8; ++t8) {
            int o = 16 * t8 + l15;
            float wv = sPar[o], bv = sPar[128 + o];
            f16x2 h00 = pk2(tanh_pre(fmaf(ua.x, wv, bv)), tanh_pre(fmaf(ua.y, wv, bv)));
            f16x2 h01 = pk2(tanh_pre(fmaf(ua.z, wv, bv)), tanh_pre(fmaf(ua.w, wv, bv)));
            f16x2 h10 = pk2(tanh_pre(fmaf(ub.x, wv, bv)), tanh_pre(fmaf(ub.y, wv, bv)));
            f16x2 h11 = pk2(tanh_pre(fmaf(ub.z, wv, bv)), tanh_pre(fmaf(ub.w, wv, bv)));
            *(f16x4*)&HT[w][o * 16 + 4 * g] = __builtin_shufflevector(h00, h01, 0, 1, 2, 3);
            *(f16x4*)&HT[w][2048 + o * 16 + 4 * g] = __builtin_shufflevector(h10, h11, 0, 1, 2, 3);
        }
    }
    // HT is wave-private; per-wave LDS ops are in-order -> no barrier needed.

    const unsigned htaddr = (unsigned)(size_t)&HT[w][0] + lane * 8;
    float p0 = 0.f, p1 = 0.f, p2 = 0.f, p3 = 0.f;
    float q0 = 0.f, q1 = 0.f, q2 = 0.f, q3 = 0.f;

#pragma unroll
    for (int lyr = 0; lyr < NHID; ++lyr) {
        // ---- all A-fragments for this layer: 16 tr-reads, one wait ----
        f16x4 r0, r1, r2, r3, r4, r5, r6, r7, r8, r9, r10, r11, r12, r13, r14, r15;
        asm volatile(
            "ds_read_b64_tr_b16 %0, %16 offset:0\n\t"
            "ds_read_b64_tr_b16 %1, %16 offset:512\n\t"
            "ds_read_b64_tr_b16 %2, %16 offset:1024\n\t"
            "ds_read_b64_tr_b16 %3, %16 offset:1536\n\t"
            "ds_read_b64_tr_b16 %4, %16 offset:2048\n\t"
            "ds_read_b64_tr_b16 %5, %16 offset:2560\n\t"
            "ds_read_b64_tr_b16 %6, %16 offset:3072\n\t"
            "ds_read_b64_tr_b16 %7, %16 offset:3584\n\t"
            "ds_read_b64_tr_b16 %8, %16 offset:4096\n\t"
            "ds_read_b64_tr_b16 %9, %16 offset:4608\n\t"
            "ds_read_b64_tr_b16 %10, %16 offset:5120\n\t"
            "ds_read_b64_tr_b16 %11, %16 offset:5632\n\t"
            "ds_read_b64_tr_b16 %12, %16 offset:6144\n\t"
            "ds_read_b64_tr_b16 %13, %16 offset:6656\n\t"
            "ds_read_b64_tr_b16 %14, %16 offset:7168\n\t"
            "ds_read_b64_tr_b16 %15, %16 offset:7680\n\t"
            "s_waitcnt lgkmcnt(0)"
            : "=v"(r0), "=v"(r1), "=v"(r2), "=v"(r3), "=v"(r4), "=v"(r5), "=v"(r6), "=v"(r7),
              "=v"(r8), "=v"(r9), "=v"(r10), "=v"(r11), "=v"(r12), "=v"(r13), "=v"(r14), "=v"(r15)
            : "v"(htaddr) : "memory");
        __builtin_amdgcn_sched_barrier(0);   // rule-18 fence
        f16x8 A0[4], A1[4];
        A0[0] = __builtin_shufflevector(r0, r1, 0, 1, 2, 3, 4, 5, 6, 7);
        A0[1] = __builtin_shufflevector(r2, r3, 0, 1, 2, 3, 4, 5, 6, 7);
        A0[2] = __builtin_shufflevector(r4, r5, 0, 1, 2, 3, 4, 5, 6, 7);
        A0[3] = __builtin_shufflevector(r6, r7, 0, 1, 2, 3, 4, 5, 6, 7);
        A1[0] = __builtin_shufflevector(r8, r9, 0, 1, 2, 3, 4, 5, 6, 7);
        A1[1] = __builtin_shufflevector(r10, r11, 0, 1, 2, 3, 4, 5, 6, 7);
        A1[2] = __builtin_shufflevector(r12, r13, 0, 1, 2, 3, 4, 5, 6, 7);
        A1[3] = __builtin_shufflevector(r14, r15, 0, 1, 2, 3, 4, 5, 6, 7);

#pragma unroll
        for (int t8 = 0; t8 < 8; ++t8) {
            const int i = lyr * 8 + t8;
            // top-of-step wait: drain this step's 4 loads (issued 2 steps ago)
            if (i < 23) asm volatile("s_waitcnt vmcnt(4)" ::: "memory");
            else        asm volatile("s_waitcnt vmcnt(0)" ::: "memory");
            __builtin_amdgcn_sched_barrier(0);

            f32x4 acc0 = (f32x4){0.f, 0.f, 0.f, 0.f};   // ZERO seed (proven); bias in epilogue
            f32x4 acc1 = (f32x4){0.f, 0.f, 0.f, 0.f};
            __builtin_amdgcn_s_setprio(1);
#pragma unroll
            for (int s = 0; s < 4; ++s) {
                U4H8 bw;
                bw.u = (i % 2 == 0) ? B0[s] : B1[s];
                acc0 = __builtin_amdgcn_mfma_f32_16x16x32_f16(A0[s], bw.h, acc0, 0, 0, 0);
                acc1 = __builtin_amdgcn_mfma_f32_16x16x32_f16(A1[s], bw.h, acc1, 0, 0, 0);
            }
            __builtin_amdgcn_s_setprio(0);
            __builtin_amdgcn_sched_barrier(0);   // keep MFMAs above the re-issue

            // re-issue the just-consumed buffer for step i+2 (cover: epilogue + 1 step)
            if (i < 22) {
                if (i % 2 == 0) { ISSUE4(B0, wfa); }
                else            { ISSUE4(B1, wfa); }
                wfa += 4096;
            }

            float bv = sPar[256 + lyr * 128 + 16 * t8 + l15];   // LDS, lgkm domain
            if (lyr < NHID - 1) {
                int o = 16 * t8 + l15;
                f16x2 h00 = pk2(tanh_pre(acc0[0] + bv), tanh_pre(acc0[1] + bv));
                f16x2 h01 = pk2(tanh_pre(acc0[2] + bv), tanh_pre(acc0[3] + bv));
                f16x2 h10 = pk2(tanh_pre(acc1[0] + bv), tanh_pre(acc1[1] + bv));
                f16x2 h11 = pk2(tanh_pre(acc1[2] + bv), tanh_pre(acc1[3] + bv));
                *(f16x4*)&HT[w][o * 16 + 4 * g] = __builtin_shufflevector(h00, h01, 0, 1, 2, 3);
                *(f16x4*)&HT[w][2048 + o * 16 + 4 * g] = __builtin_shufflevector(h10, h11, 0, 1, 2, 3);
            } else {
                float wv = sPar[640 + 16 * t8 + l15];
                p0 = fmaf(wv, tanh_pre(acc0[0] + bv), p0);
                p1 = fmaf(wv, tanh_pre(acc0[1] + bv), p1);
                p2 = fmaf(wv, tanh_pre(acc0[2] + bv), p2);
                p3 = fmaf(wv, tanh_pre(acc0[3] + bv), p3);
                q0 = fmaf(wv, tanh_pre(acc1[0] + bv), q0);
                q1 = fmaf(wv, tanh_pre(acc1[1] + bv), q1);
                q2 = fmaf(wv, tanh_pre(acc1[2] + bv), q2);
                q3 = fmaf(wv, tanh_pre(acc1[3] + bv), q3);
            }
        }
    }

    // reduce over the 16 lanes (l15 bits) of each point-group
#pragma unroll
    for (int m = 1; m < 16; m <<= 1) {
        p0 += __shfl_xor(p0, m); p1 += __shfl_xor(p1, m);
        p2 += __shfl_xor(p2, m); p3 += __shfl_xor(p3, m);
        q0 += __shfl_xor(q0, m); q1 += __shfl_xor(q1, m);
        q2 += __shfl_xor(q2, m); q3 += __shfl_xor(q3, m);
    }
    if (l15 < 4) {
        float bo = sPar[768];
        float v0 = ((l15 == 0) ? p0 : (l15 == 1) ? p1 : (l15 == 2) ? p2 : p3) + bo;
        float v1 = ((l15 == 0) ? q0 : (l15 == 1) ? q1 : (l15 == 2) ? q2 : q3) + bo;
        int pl0 = w * 32 + 4 * g + l15;
        int pl1 = pl0 + 16;
        int pid0 = lTid[pl0], pid1 = lTid[pl1];
        if (pid0 >= 0) atomicAdd(out + pid0, lWgt[pl0] * v0);  // <=2 addends: deterministic
        if (pid1 >= 0) atomicAdd(out + pid1, lWgt[pl1] * v1);
    }
}

extern "C" void kernel_launch(void* const* d_in, const int* in_sizes, int n_in,
                              void* d_out, int out_size, void* d_ws, size_t ws_size,
                              hipStream_t stream) {
    const float* x       = (const float*)d_in[0];
    const float* W_in    = (const float*)d_in[1];
    const float* b_in    = (const float*)d_in[2];
    const float* W_hid   = (const float*)d_in[3];
    const float* b_hid   = (const float*)d_in[4];
    const float* W_out   = (const float*)d_in[5];
    const float* b_out   = (const float*)d_in[6];
    const float* centers = (const float*)d_in[7];
    const float* scales  = (const float*)d_in[8];
    float* out = (float*)d_out;

    char* ws = (char*)d_ws;
    int* cursors = (int*)(ws);
    int* tasks   = (int*)(ws + TASKS_OFF);
    uint4* WfU4  = (uint4*)(ws + WF_OFF);

    (void)hipMemsetAsync(ws, 0, 256, stream);

    k_prep<<<dim3(96 + NPTS / 256), dim3(256), 0, stream>>>(W_hid, WfU4, x, cursors,
                                                            tasks, out, NPTS);
    k_mlp<<<dim3(TPB, NS), dim3(TMLP), 0, stream>>>(x, W_in, b_in, b_hid, W_out, b_out,
                                                    centers, scales, cursors, tasks,
                                                    WfU4, out);
}